// Round 1
// baseline (1668.852 us; speedup 1.0000x reference)
//
#include <hip/hip_runtime.h>

#define NNODES 50000
#define NEDGES 800000
#define HD 128            // HEADS*OUT_DIM
#define NEG 0.2f

// ---------------------------------------------------------------------------
// Kernel 1: h = x @ W^T  (N x 128) and fused per-node attention dots
//   a_src[n,h] = sum_d h[n,h,d]*att_src[h,d];  a_dst likewise.
// W (128x128) staged in LDS with ld=132 padding (bank spread + float4 align).
// Block = 256 threads, tile = 16 rows. o = tid&127 (output col), 8 rows/thread.
// ---------------------------------------------------------------------------
__global__ __launch_bounds__(256) void gat_gemm(
    const float* __restrict__ x, const float* __restrict__ W,
    const float* __restrict__ att_src, const float* __restrict__ att_dst,
    float* __restrict__ h, float* __restrict__ asrc, float* __restrict__ adst)
{
    __shared__ float Ws[128 * 132];
    __shared__ float xs[16 * 132];
    const int t = threadIdx.x;
    const int rowBase = blockIdx.x * 16;

    for (int idx = t * 4; idx < 128 * 128; idx += 1024) {
        int r = idx >> 7, c = idx & 127;
        *(float4*)(Ws + r * 132 + c) = *(const float4*)(W + idx);
    }
    for (int idx = t * 4; idx < 16 * 128; idx += 1024) {
        int r = idx >> 7, c = idx & 127;
        *(float4*)(xs + r * 132 + c) =
            *(const float4*)(x + (size_t)(rowBase + r) * 128 + c);
    }
    __syncthreads();

    const int o  = t & 127;   // output column 0..127
    const int r2 = t >> 7;    // row phase 0..1
    float acc[8];
#pragma unroll
    for (int rr = 0; rr < 8; rr++) acc[rr] = 0.f;

    for (int i = 0; i < 128; i += 4) {
        float4 wv = *(const float4*)(Ws + o * 132 + i);
#pragma unroll
        for (int rr = 0; rr < 8; rr++) {
            float4 xv = *(const float4*)(xs + (r2 + 2 * rr) * 132 + i);
            acc[rr] = fmaf(wv.x, xv.x, acc[rr]);
            acc[rr] = fmaf(wv.y, xv.y, acc[rr]);
            acc[rr] = fmaf(wv.z, xv.z, acc[rr]);
            acc[rr] = fmaf(wv.w, xv.w, acc[rr]);
        }
    }

    const float av_s = att_src[o];
    const float av_d = att_dst[o];
#pragma unroll
    for (int rr = 0; rr < 8; rr++) {
        const int n = rowBase + r2 + 2 * rr;
        h[(size_t)n * HD + o] = acc[rr];
        float vs = acc[rr] * av_s;
        float vd = acc[rr] * av_d;
        // reduce across the 32 lanes of each head group (o = head*32 + d)
#pragma unroll
        for (int m = 16; m >= 1; m >>= 1) {
            vs += __shfl_xor(vs, m, 64);
            vd += __shfl_xor(vd, m, 64);
        }
        if ((o & 31) == 0) {
            int head = o >> 5;   // 0..3
            asrc[n * 4 + head] = vs;
            adst[n * 4 + head] = vd;
        }
    }
}

// ---------------------------------------------------------------------------
// Kernel 2: out[n, :] = bias[:]  (accumulator init; bias is (128,))
// One float4 per thread over N*128 floats.
// ---------------------------------------------------------------------------
__global__ __launch_bounds__(256) void gat_init_out(
    const float* __restrict__ bias, float* __restrict__ out)
{
    int i = blockIdx.x * 256 + threadIdx.x;       // float4 index
    float4 bv = *(const float4*)(bias + (i & 31) * 4);
    ((float4*)out)[i] = bv;
}

// ---------------------------------------------------------------------------
// Kernel 3: per-edge exp(leaky_relu(a_src[src]+a_dst[dst])) summed into
// ssum[dst, head]. Softmax max-shift omitted (shift-invariant; alpha ~ O(6)).
// ---------------------------------------------------------------------------
__global__ __launch_bounds__(256) void gat_edge_sum(
    const int* __restrict__ ei, const float* __restrict__ asrc,
    const float* __restrict__ adst, float* __restrict__ ssum)
{
    int e = blockIdx.x * 256 + threadIdx.x;
    int s = ei[e], d = ei[NEDGES + e];
    float4 a = *(const float4*)(asrc + s * 4);
    float4 b = *(const float4*)(adst + d * 4);
    float al;
    al = a.x + b.x; al = (al > 0.f) ? al : NEG * al; float e0 = __expf(al);
    al = a.y + b.y; al = (al > 0.f) ? al : NEG * al; float e1 = __expf(al);
    al = a.z + b.z; al = (al > 0.f) ? al : NEG * al; float e2 = __expf(al);
    al = a.w + b.w; al = (al > 0.f) ? al : NEG * al; float e3 = __expf(al);
    float* p = ssum + d * 4;
    atomicAdd(p + 0, e0);
    atomicAdd(p + 1, e1);
    atomicAdd(p + 2, e2);
    atomicAdd(p + 3, e3);
}

// ---------------------------------------------------------------------------
// Kernel 4: scatter  out[dst] += h[src] * alpha  ;  alpha_pooled[e].
// 32 lanes per edge; lane k handles cols 4k..4k+3 (head = k>>3).
// Edge weights recomputed (identical fp ops to kernel 3 -> consistent).
// ---------------------------------------------------------------------------
__global__ __launch_bounds__(256) void gat_edge_scatter(
    const int* __restrict__ ei, const float* __restrict__ asrc,
    const float* __restrict__ adst, const float* __restrict__ ssum,
    const float* __restrict__ h, float* __restrict__ out,
    float* __restrict__ apool)
{
    int t = threadIdx.x;
    int e = blockIdx.x * 8 + (t >> 5);
    int k = t & 31;
    int s = ei[e], d = ei[NEDGES + e];
    float4 a  = *(const float4*)(asrc + s * 4);
    float4 b  = *(const float4*)(adst + d * 4);
    float4 sv = *(const float4*)(ssum + d * 4);
    float al;
    al = a.x + b.x; al = (al > 0.f) ? al : NEG * al; float w0 = __expf(al) / (sv.x + 1e-16f);
    al = a.y + b.y; al = (al > 0.f) ? al : NEG * al; float w1 = __expf(al) / (sv.y + 1e-16f);
    al = a.z + b.z; al = (al > 0.f) ? al : NEG * al; float w2 = __expf(al) / (sv.z + 1e-16f);
    al = a.w + b.w; al = (al > 0.f) ? al : NEG * al; float w3 = __expf(al) / (sv.w + 1e-16f);
    if (k == 0) apool[e] = 0.25f * (w0 + w1 + w2 + w3);

    float wsel = (k < 16) ? ((k < 8) ? w0 : w1) : ((k < 24) ? w2 : w3);
    float4 hv = *(const float4*)(h + (size_t)s * HD + k * 4);
    float* op = out + (size_t)d * HD + k * 4;
    atomicAdd(op + 0, hv.x * wsel);
    atomicAdd(op + 1, hv.y * wsel);
    atomicAdd(op + 2, hv.z * wsel);
    atomicAdd(op + 3, hv.w * wsel);
}

// ---------------------------------------------------------------------------
extern "C" void kernel_launch(void* const* d_in, const int* in_sizes, int n_in,
                              void* d_out, int out_size, void* d_ws, size_t ws_size,
                              hipStream_t stream)
{
    const float* x       = (const float*)d_in[0];
    const int*   ei      = (const int*)d_in[1];
    const float* W       = (const float*)d_in[2];
    const float* att_src = (const float*)d_in[3];
    const float* att_dst = (const float*)d_in[4];
    const float* bias    = (const float*)d_in[5];

    float* out   = (float*)d_out;                    // (N,128)
    float* apool = out + (size_t)NNODES * HD;        // (E,)

    // workspace: h (6.4M) | asrc (200K) | adst (200K) | ssum (200K) floats
    float* h    = (float*)d_ws;
    float* asrc = h + (size_t)NNODES * HD;
    float* adst = asrc + NNODES * 4;
    float* ssum = adst + NNODES * 4;

    hipMemsetAsync(ssum, 0, (size_t)NNODES * 4 * sizeof(float), stream);
    gat_init_out<<<(NNODES * HD) / 1024, 256, 0, stream>>>(bias, out);
    gat_gemm<<<NNODES / 16, 256, 0, stream>>>(x, W, att_src, att_dst, h, asrc, adst);
    gat_edge_sum<<<NEDGES / 256, 256, 0, stream>>>(ei, asrc, adst, ssum);
    gat_edge_scatter<<<NEDGES / 8, 256, 0, stream>>>(ei, asrc, adst, ssum, h, out, apool);
}

// Round 2
// 560.042 us; speedup vs baseline: 2.9799x; 2.9799x over previous
//
#include <hip/hip_runtime.h>

#define NNODES 50000
#define NEDGES 800000
#define HD 128            // HEADS*OUT_DIM
#define NEG 0.2f

// ---------------------------------------------------------------------------
// Kernel 1: h = x @ W^T  (N x 128) and fused per-node attention dots.
// W (128x128) staged in LDS with ld=132 padding. Block=256, tile=16 rows.
// ---------------------------------------------------------------------------
__global__ __launch_bounds__(256) void gat_gemm(
    const float* __restrict__ x, const float* __restrict__ W,
    const float* __restrict__ att_src, const float* __restrict__ att_dst,
    float* __restrict__ h, float* __restrict__ asrc, float* __restrict__ adst)
{
    __shared__ float Ws[128 * 132];
    __shared__ float xs[16 * 132];
    const int t = threadIdx.x;
    const int rowBase = blockIdx.x * 16;

    for (int idx = t * 4; idx < 128 * 128; idx += 1024) {
        int r = idx >> 7, c = idx & 127;
        *(float4*)(Ws + r * 132 + c) = *(const float4*)(W + idx);
    }
    for (int idx = t * 4; idx < 16 * 128; idx += 1024) {
        int r = idx >> 7, c = idx & 127;
        *(float4*)(xs + r * 132 + c) =
            *(const float4*)(x + (size_t)(rowBase + r) * 128 + c);
    }
    __syncthreads();

    const int o  = t & 127;   // output column 0..127
    const int r2 = t >> 7;    // row phase 0..1
    float acc[8];
#pragma unroll
    for (int rr = 0; rr < 8; rr++) acc[rr] = 0.f;

    for (int i = 0; i < 128; i += 4) {
        float4 wv = *(const float4*)(Ws + o * 132 + i);
#pragma unroll
        for (int rr = 0; rr < 8; rr++) {
            float4 xv = *(const float4*)(xs + (r2 + 2 * rr) * 132 + i);
            acc[rr] = fmaf(wv.x, xv.x, acc[rr]);
            acc[rr] = fmaf(wv.y, xv.y, acc[rr]);
            acc[rr] = fmaf(wv.z, xv.z, acc[rr]);
            acc[rr] = fmaf(wv.w, xv.w, acc[rr]);
        }
    }

    const float av_s = att_src[o];
    const float av_d = att_dst[o];
#pragma unroll
    for (int rr = 0; rr < 8; rr++) {
        const int n = rowBase + r2 + 2 * rr;
        h[(size_t)n * HD + o] = acc[rr];
        float vs = acc[rr] * av_s;
        float vd = acc[rr] * av_d;
#pragma unroll
        for (int m = 16; m >= 1; m >>= 1) {
            vs += __shfl_xor(vs, m, 64);
            vd += __shfl_xor(vd, m, 64);
        }
        if ((o & 31) == 0) {
            int head = o >> 5;
            asrc[n * 4 + head] = vs;
            adst[n * 4 + head] = vd;
        }
    }
}

// ---------------------------------------------------------------------------
// Kernel 2: per-edge exp(leaky_relu(.)) -> ssum[dst,head]; also deg[dst]++.
// Softmax max-shift omitted (shift-invariant; alpha magnitudes are O(6)).
// ---------------------------------------------------------------------------
__global__ __launch_bounds__(256) void gat_edge_sum(
    const int* __restrict__ ei, const float* __restrict__ asrc,
    const float* __restrict__ adst, float* __restrict__ ssum,
    int* __restrict__ deg)
{
    int e = blockIdx.x * 256 + threadIdx.x;
    int s = ei[e], d = ei[NEDGES + e];
    float4 a = *(const float4*)(asrc + s * 4);
    float4 b = *(const float4*)(adst + d * 4);
    float al;
    al = a.x + b.x; al = (al > 0.f) ? al : NEG * al; float e0 = __expf(al);
    al = a.y + b.y; al = (al > 0.f) ? al : NEG * al; float e1 = __expf(al);
    al = a.z + b.z; al = (al > 0.f) ? al : NEG * al; float e2 = __expf(al);
    al = a.w + b.w; al = (al > 0.f) ? al : NEG * al; float e3 = __expf(al);
    float* p = ssum + d * 4;
    atomicAdd(p + 0, e0);
    atomicAdd(p + 1, e1);
    atomicAdd(p + 2, e2);
    atomicAdd(p + 3, e3);
    atomicAdd(deg + d, 1);
}

// ---------------------------------------------------------------------------
// Kernel 3: exclusive scan of deg -> coff[0..N] (single block, 1024 threads).
// ---------------------------------------------------------------------------
__global__ __launch_bounds__(1024) void gat_scan(
    const int* __restrict__ deg, int* __restrict__ coff)
{
    __shared__ int partial[1024];
    const int t = threadIdx.x;
    const int CH = (NNODES + 1023) / 1024;   // 49
    const int base = t * CH;
    int sum = 0;
    for (int i = 0; i < CH; i++) {
        int idx = base + i;
        if (idx < NNODES) sum += deg[idx];
    }
    partial[t] = sum;
    __syncthreads();
    for (int off = 1; off < 1024; off <<= 1) {
        int v = (t >= off) ? partial[t - off] : 0;
        __syncthreads();
        partial[t] += v;
        __syncthreads();
    }
    int run = (t == 0) ? 0 : partial[t - 1];
    for (int i = 0; i < CH; i++) {
        int idx = base + i;
        if (idx < NNODES) { coff[idx] = run; run += deg[idx]; }
    }
    if (t == 1023) coff[NNODES] = run;
}

// ---------------------------------------------------------------------------
// Kernel 4: fill CSR buckets + write alpha_pooled.
// pos = coff[d] + cursor[d]++;  csr_src[pos]=s; csr_w[pos]=normalized w4.
// ---------------------------------------------------------------------------
__global__ __launch_bounds__(256) void gat_fill(
    const int* __restrict__ ei, const float* __restrict__ asrc,
    const float* __restrict__ adst, const float* __restrict__ ssum,
    const int* __restrict__ coff, int* __restrict__ cursor,
    int* __restrict__ csr_src, float* __restrict__ csr_w,
    float* __restrict__ apool)
{
    int e = blockIdx.x * 256 + threadIdx.x;
    int s = ei[e], d = ei[NEDGES + e];
    float4 a  = *(const float4*)(asrc + s * 4);
    float4 b  = *(const float4*)(adst + d * 4);
    float4 sv = *(const float4*)(ssum + d * 4);
    float al;
    al = a.x + b.x; al = (al > 0.f) ? al : NEG * al; float w0 = __expf(al) / (sv.x + 1e-16f);
    al = a.y + b.y; al = (al > 0.f) ? al : NEG * al; float w1 = __expf(al) / (sv.y + 1e-16f);
    al = a.z + b.z; al = (al > 0.f) ? al : NEG * al; float w2 = __expf(al) / (sv.z + 1e-16f);
    al = a.w + b.w; al = (al > 0.f) ? al : NEG * al; float w3 = __expf(al) / (sv.w + 1e-16f);
    apool[e] = 0.25f * (w0 + w1 + w2 + w3);
    int pos = coff[d] + atomicAdd(cursor + d, 1);
    csr_src[pos] = s;
    *(float4*)(csr_w + (size_t)pos * 4) = make_float4(w0, w1, w2, w3);
}

// ---------------------------------------------------------------------------
// Kernel 5: gather.  out[n,:] = bias + sum_j csr_w[j,head] * h[csr_src[j],:]
// 32 lanes per node (lane k -> cols 4k..4k+3, head = k>>3); 8 nodes/block.
// Register accumulation; exactly one write of out per element. No atomics.
// ---------------------------------------------------------------------------
__global__ __launch_bounds__(256) void gat_gather(
    const int* __restrict__ coff, const int* __restrict__ csr_src,
    const float* __restrict__ csr_w, const float* __restrict__ h,
    const float* __restrict__ bias, float* __restrict__ out)
{
    int t = threadIdx.x;
    int n = blockIdx.x * 8 + (t >> 5);
    int k = t & 31;
    int head = k >> 3;
    if (n >= NNODES) return;
    int beg = coff[n], end = coff[n + 1];
    float4 acc = *(const float4*)(bias + k * 4);
    for (int j = beg; j < end; j++) {
        int s = csr_src[j];                       // wave-broadcast load
        float w = csr_w[(size_t)j * 4 + head];
        float4 hv = *(const float4*)(h + (size_t)s * HD + k * 4);
        acc.x = fmaf(hv.x, w, acc.x);
        acc.y = fmaf(hv.y, w, acc.y);
        acc.z = fmaf(hv.z, w, acc.z);
        acc.w = fmaf(hv.w, w, acc.w);
    }
    *(float4*)(out + (size_t)n * HD + k * 4) = acc;
}

// ---------------------------------------------------------------------------
extern "C" void kernel_launch(void* const* d_in, const int* in_sizes, int n_in,
                              void* d_out, int out_size, void* d_ws, size_t ws_size,
                              hipStream_t stream)
{
    const float* x       = (const float*)d_in[0];
    const int*   ei      = (const int*)d_in[1];
    const float* W       = (const float*)d_in[2];
    const float* att_src = (const float*)d_in[3];
    const float* att_dst = (const float*)d_in[4];
    const float* bias    = (const float*)d_in[5];

    float* out   = (float*)d_out;                    // (N,128)
    float* apool = out + (size_t)NNODES * HD;        // (E,)

    // workspace layout (floats/ints), ~43 MB total
    float* h      = (float*)d_ws;                    // N*128
    float* asrc   = h + (size_t)NNODES * HD;         // N*4
    float* adst   = asrc + NNODES * 4;               // N*4
    float* ssum   = adst + NNODES * 4;               // N*4
    int*   deg    = (int*)(ssum + NNODES * 4);       // N
    int*   coff   = deg + NNODES;                    // N+1
    int*   cursor = coff + NNODES + 1;               // N
    int*   csrsrc = cursor + NNODES;                 // E
    float* csrw   = (float*)(csrsrc + NEDGES);       // E*4

    hipMemsetAsync(ssum, 0, (size_t)NNODES * 4 * sizeof(float), stream);
    hipMemsetAsync(deg, 0, (size_t)NNODES * sizeof(int), stream);
    hipMemsetAsync(cursor, 0, (size_t)NNODES * sizeof(int), stream);

    gat_gemm<<<NNODES / 16, 256, 0, stream>>>(x, W, att_src, att_dst, h, asrc, adst);
    gat_edge_sum<<<NEDGES / 256, 256, 0, stream>>>(ei, asrc, adst, ssum, deg);
    gat_scan<<<1, 1024, 0, stream>>>(deg, coff);
    gat_fill<<<NEDGES / 256, 256, 0, stream>>>(ei, asrc, adst, ssum, coff, cursor,
                                               csrsrc, csrw, apool);
    gat_gather<<<(NNODES + 7) / 8, 256, 0, stream>>>(coff, csrsrc, csrw, h, bias, out);
}

// Round 3
// 392.579 us; speedup vs baseline: 4.2510x; 1.4266x over previous
//
#include <hip/hip_runtime.h>

#define NNODES 50000
#define NEDGES 800000
#define HD 128            // HEADS*OUT_DIM
#define NEG 0.2f

// ---------------------------------------------------------------------------
// Kernel 1: h = x @ W^T  (N x 128) and fused per-node attention dots.
// W (128x128) staged in LDS with ld=132 padding. Block=256, tile=16 rows.
// ---------------------------------------------------------------------------
__global__ __launch_bounds__(256) void gat_gemm(
    const float* __restrict__ x, const float* __restrict__ W,
    const float* __restrict__ att_src, const float* __restrict__ att_dst,
    float* __restrict__ h, float* __restrict__ asrc, float* __restrict__ adst)
{
    __shared__ float Ws[128 * 132];
    __shared__ float xs[16 * 132];
    const int t = threadIdx.x;
    const int rowBase = blockIdx.x * 16;

    for (int idx = t * 4; idx < 128 * 128; idx += 1024) {
        int r = idx >> 7, c = idx & 127;
        *(float4*)(Ws + r * 132 + c) = *(const float4*)(W + idx);
    }
    for (int idx = t * 4; idx < 16 * 128; idx += 1024) {
        int r = idx >> 7, c = idx & 127;
        *(float4*)(xs + r * 132 + c) =
            *(const float4*)(x + (size_t)(rowBase + r) * 128 + c);
    }
    __syncthreads();

    const int o  = t & 127;   // output column 0..127
    const int r2 = t >> 7;    // row phase 0..1
    float acc[8];
#pragma unroll
    for (int rr = 0; rr < 8; rr++) acc[rr] = 0.f;

    for (int i = 0; i < 128; i += 4) {
        float4 wv = *(const float4*)(Ws + o * 132 + i);
#pragma unroll
        for (int rr = 0; rr < 8; rr++) {
            float4 xv = *(const float4*)(xs + (r2 + 2 * rr) * 132 + i);
            acc[rr] = fmaf(wv.x, xv.x, acc[rr]);
            acc[rr] = fmaf(wv.y, xv.y, acc[rr]);
            acc[rr] = fmaf(wv.z, xv.z, acc[rr]);
            acc[rr] = fmaf(wv.w, xv.w, acc[rr]);
        }
    }

    const float av_s = att_src[o];
    const float av_d = att_dst[o];
#pragma unroll
    for (int rr = 0; rr < 8; rr++) {
        const int n = rowBase + r2 + 2 * rr;
        h[(size_t)n * HD + o] = acc[rr];
        float vs = acc[rr] * av_s;
        float vd = acc[rr] * av_d;
#pragma unroll
        for (int m = 16; m >= 1; m >>= 1) {
            vs += __shfl_xor(vs, m, 64);
            vd += __shfl_xor(vd, m, 64);
        }
        if ((o & 31) == 0) {
            int head = o >> 5;
            asrc[n * 4 + head] = vs;
            adst[n * 4 + head] = vd;
        }
    }
}

// ---------------------------------------------------------------------------
// Kernel 2: degree histogram. The returned old value IS the edge's rank
// within its dst bucket -> no cursor atomics needed later.
// ---------------------------------------------------------------------------
__global__ __launch_bounds__(256) void gat_deg(
    const int* __restrict__ ei, int* __restrict__ deg, int* __restrict__ rank)
{
    int e = blockIdx.x * 256 + threadIdx.x;
    int d = ei[NEDGES + e];
    rank[e] = atomicAdd(deg + d, 1);
}

// ---------------------------------------------------------------------------
// Kernel 3: exclusive scan of deg -> coff[0..N] (single block, 1024 threads).
// ---------------------------------------------------------------------------
__global__ __launch_bounds__(1024) void gat_scan(
    const int* __restrict__ deg, int* __restrict__ coff)
{
    __shared__ int partial[1024];
    const int t = threadIdx.x;
    const int CH = (NNODES + 1023) / 1024;   // 49
    const int base = t * CH;
    int sum = 0;
    for (int i = 0; i < CH; i++) {
        int idx = base + i;
        if (idx < NNODES) sum += deg[idx];
    }
    partial[t] = sum;
    __syncthreads();
    for (int off = 1; off < 1024; off <<= 1) {
        int v = (t >= off) ? partial[t - off] : 0;
        __syncthreads();
        partial[t] += v;
        __syncthreads();
    }
    int run = (t == 0) ? 0 : partial[t - 1];
    for (int i = 0; i < CH; i++) {
        int idx = base + i;
        if (idx < NNODES) { coff[idx] = run; run += deg[idx]; }
    }
    if (t == 1023) coff[NNODES] = run;
}

// ---------------------------------------------------------------------------
// Kernel 4: CSR fill — NO atomics. pos = coff[d] + rank[e].
// Stores unnormalized exp weights (float4) + src id.
// ---------------------------------------------------------------------------
__global__ __launch_bounds__(256) void gat_fill(
    const int* __restrict__ ei, const int* __restrict__ rank,
    const float* __restrict__ asrc, const float* __restrict__ adst,
    const int* __restrict__ coff,
    int* __restrict__ csr_src, float* __restrict__ csr_w)
{
    int e = blockIdx.x * 256 + threadIdx.x;
    int s = ei[e], d = ei[NEDGES + e];
    float4 a = *(const float4*)(asrc + s * 4);
    float4 b = *(const float4*)(adst + d * 4);
    float al;
    al = a.x + b.x; al = (al > 0.f) ? al : NEG * al; float e0 = __expf(al);
    al = a.y + b.y; al = (al > 0.f) ? al : NEG * al; float e1 = __expf(al);
    al = a.z + b.z; al = (al > 0.f) ? al : NEG * al; float e2 = __expf(al);
    al = a.w + b.w; al = (al > 0.f) ? al : NEG * al; float e3 = __expf(al);
    int pos = coff[d] + rank[e];
    csr_src[pos] = s;
    *(float4*)(csr_w + (size_t)pos * 4) = make_float4(e0, e1, e2, e3);
}

// ---------------------------------------------------------------------------
// Kernel 5: per-node — sum bucket weights (contiguous), store ssum, then
// normalize + gather h[src] + write out exactly once. No fp atomics.
// 32 lanes per node (lane k -> cols 4k..4k+3, head = k>>3); 8 nodes/block.
// ---------------------------------------------------------------------------
__global__ __launch_bounds__(256) void gat_node(
    const int* __restrict__ coff, const int* __restrict__ csr_src,
    const float* __restrict__ csr_w, const float* __restrict__ h,
    const float* __restrict__ bias, float* __restrict__ out,
    float* __restrict__ ssum)
{
    int t = threadIdx.x;
    int n = blockIdx.x * 8 + (t >> 5);
    int k = t & 31;
    int head = k >> 3;
    if (n >= NNODES) return;
    int beg = coff[n], end = coff[n + 1];

    // phase 1: per-head weight sums (lanes stride the bucket, then reduce)
    float4 sum = make_float4(0.f, 0.f, 0.f, 0.f);
    for (int j = beg + k; j < end; j += 32) {
        float4 wv = *(const float4*)(csr_w + (size_t)j * 4);
        sum.x += wv.x; sum.y += wv.y; sum.z += wv.z; sum.w += wv.w;
    }
#pragma unroll
    for (int m = 16; m >= 1; m >>= 1) {
        sum.x += __shfl_xor(sum.x, m, 64);
        sum.y += __shfl_xor(sum.y, m, 64);
        sum.z += __shfl_xor(sum.z, m, 64);
        sum.w += __shfl_xor(sum.w, m, 64);
    }
    if (k == 0) *(float4*)(ssum + n * 4) = sum;
    float rs[4];
    rs[0] = 1.f / (sum.x + 1e-16f);
    rs[1] = 1.f / (sum.y + 1e-16f);
    rs[2] = 1.f / (sum.z + 1e-16f);
    rs[3] = 1.f / (sum.w + 1e-16f);
    const float rsel = rs[head];

    // phase 2: gather + accumulate
    float4 acc = *(const float4*)(bias + k * 4);
    for (int j = beg; j < end; j++) {
        int s = csr_src[j];                               // broadcast load
        float w = csr_w[(size_t)j * 4 + head] * rsel;
        float4 hv = *(const float4*)(h + (size_t)s * HD + k * 4);
        acc.x = fmaf(hv.x, w, acc.x);
        acc.y = fmaf(hv.y, w, acc.y);
        acc.z = fmaf(hv.z, w, acc.z);
        acc.w = fmaf(hv.w, w, acc.w);
    }
    *(float4*)(out + (size_t)n * HD + k * 4) = acc;
}

// ---------------------------------------------------------------------------
// Kernel 6: alpha_pooled, edge-order (coalesced writes); recomputes exp from
// LLC-resident asrc/adst/ssum.
// ---------------------------------------------------------------------------
__global__ __launch_bounds__(256) void gat_apool(
    const int* __restrict__ ei, const float* __restrict__ asrc,
    const float* __restrict__ adst, const float* __restrict__ ssum,
    float* __restrict__ apool)
{
    int e = blockIdx.x * 256 + threadIdx.x;
    int s = ei[e], d = ei[NEDGES + e];
    float4 a  = *(const float4*)(asrc + s * 4);
    float4 b  = *(const float4*)(adst + d * 4);
    float4 sv = *(const float4*)(ssum + d * 4);
    float al;
    al = a.x + b.x; al = (al > 0.f) ? al : NEG * al; float w0 = __expf(al) / (sv.x + 1e-16f);
    al = a.y + b.y; al = (al > 0.f) ? al : NEG * al; float w1 = __expf(al) / (sv.y + 1e-16f);
    al = a.z + b.z; al = (al > 0.f) ? al : NEG * al; float w2 = __expf(al) / (sv.z + 1e-16f);
    al = a.w + b.w; al = (al > 0.f) ? al : NEG * al; float w3 = __expf(al) / (sv.w + 1e-16f);
    apool[e] = 0.25f * (w0 + w1 + w2 + w3);
}

// ---------------------------------------------------------------------------
extern "C" void kernel_launch(void* const* d_in, const int* in_sizes, int n_in,
                              void* d_out, int out_size, void* d_ws, size_t ws_size,
                              hipStream_t stream)
{
    const float* x       = (const float*)d_in[0];
    const int*   ei      = (const int*)d_in[1];
    const float* W       = (const float*)d_in[2];
    const float* att_src = (const float*)d_in[3];
    const float* att_dst = (const float*)d_in[4];
    const float* bias    = (const float*)d_in[5];

    float* out   = (float*)d_out;                    // (N,128)
    float* apool = out + (size_t)NNODES * HD;        // (E,)

    // workspace layout (all 16B-aligned chunks), ~48 MB total
    float* h      = (float*)d_ws;                    // N*128
    float* asrc   = h + (size_t)NNODES * HD;         // N*4
    float* adst   = asrc + NNODES * 4;               // N*4
    float* ssum   = adst + NNODES * 4;               // N*4
    float* csrw   = ssum + NNODES * 4;               // E*4
    int*   deg    = (int*)(csrw + (size_t)NEDGES * 4); // N
    int*   coff   = deg + NNODES;                    // N+1
    int*   rank   = coff + NNODES + 1;               // E
    int*   csrsrc = rank + NEDGES;                   // E

    hipMemsetAsync(deg, 0, (size_t)NNODES * sizeof(int), stream);

    gat_gemm<<<NNODES / 16, 256, 0, stream>>>(x, W, att_src, att_dst, h, asrc, adst);
    gat_deg<<<NEDGES / 256, 256, 0, stream>>>(ei, deg, rank);
    gat_scan<<<1, 1024, 0, stream>>>(deg, coff);
    gat_fill<<<NEDGES / 256, 256, 0, stream>>>(ei, rank, asrc, adst, coff, csrsrc, csrw);
    gat_node<<<(NNODES + 7) / 8, 256, 0, stream>>>(coff, csrsrc, csrw, h, bias, out, ssum);
    gat_apool<<<NEDGES / 256, 256, 0, stream>>>(ei, asrc, adst, ssum, apool);
}

// Round 4
// 305.303 us; speedup vs baseline: 5.4662x; 1.2859x over previous
//
#include <hip/hip_runtime.h>

#define NNODES 50000
#define NEDGES 800000
#define HD 128            // HEADS*OUT_DIM
#define NEG 0.2f
#define SCAN_BLOCKS ((NNODES + 255) / 256)   // 196

// ---------------------------------------------------------------------------
// Kernel 1: h = x @ W^T  (N x 128) and fused per-node attention dots.
// W (128x128) staged in LDS with ld=132 padding. Block=256, tile=16 rows.
// ---------------------------------------------------------------------------
__global__ __launch_bounds__(256) void gat_gemm(
    const float* __restrict__ x, const float* __restrict__ W,
    const float* __restrict__ att_src, const float* __restrict__ att_dst,
    float* __restrict__ h, float* __restrict__ asrc, float* __restrict__ adst)
{
    __shared__ float Ws[128 * 132];
    __shared__ float xs[16 * 132];
    const int t = threadIdx.x;
    const int rowBase = blockIdx.x * 16;

    for (int idx = t * 4; idx < 128 * 128; idx += 1024) {
        int r = idx >> 7, c = idx & 127;
        *(float4*)(Ws + r * 132 + c) = *(const float4*)(W + idx);
    }
    for (int idx = t * 4; idx < 16 * 128; idx += 1024) {
        int r = idx >> 7, c = idx & 127;
        *(float4*)(xs + r * 132 + c) =
            *(const float4*)(x + (size_t)(rowBase + r) * 128 + c);
    }
    __syncthreads();

    const int o  = t & 127;   // output column 0..127
    const int r2 = t >> 7;    // row phase 0..1
    float acc[8];
#pragma unroll
    for (int rr = 0; rr < 8; rr++) acc[rr] = 0.f;

    for (int i = 0; i < 128; i += 4) {
        float4 wv = *(const float4*)(Ws + o * 132 + i);
#pragma unroll
        for (int rr = 0; rr < 8; rr++) {
            float4 xv = *(const float4*)(xs + (r2 + 2 * rr) * 132 + i);
            acc[rr] = fmaf(wv.x, xv.x, acc[rr]);
            acc[rr] = fmaf(wv.y, xv.y, acc[rr]);
            acc[rr] = fmaf(wv.z, xv.z, acc[rr]);
            acc[rr] = fmaf(wv.w, xv.w, acc[rr]);
        }
    }

    const float av_s = att_src[o];
    const float av_d = att_dst[o];
#pragma unroll
    for (int rr = 0; rr < 8; rr++) {
        const int n = rowBase + r2 + 2 * rr;
        h[(size_t)n * HD + o] = acc[rr];
        float vs = acc[rr] * av_s;
        float vd = acc[rr] * av_d;
#pragma unroll
        for (int m = 16; m >= 1; m >>= 1) {
            vs += __shfl_xor(vs, m, 64);
            vd += __shfl_xor(vd, m, 64);
        }
        if ((o & 31) == 0) {
            int head = o >> 5;
            asrc[n * 4 + head] = vs;
            adst[n * 4 + head] = vd;
        }
    }
}

// ---------------------------------------------------------------------------
// Kernel 2: degree histogram. Returned old value = edge's in-bucket rank.
// ---------------------------------------------------------------------------
__global__ __launch_bounds__(256) void gat_deg(
    const int* __restrict__ ei, int* __restrict__ deg, int* __restrict__ rank)
{
    int e = blockIdx.x * 256 + threadIdx.x;
    int d = ei[NEDGES + e];
    rank[e] = atomicAdd(deg + d, 1);
}

// ---------------------------------------------------------------------------
// Hierarchical exclusive scan of deg -> coff.
// scan1: block-local exclusive scan to coff + block sums.
// scan2: single block scans the 196 block sums.
// scan3: add block offsets; coff[N] = NEDGES (known statically).
// ---------------------------------------------------------------------------
__global__ __launch_bounds__(256) void gat_scan1(
    const int* __restrict__ deg, int* __restrict__ coff, int* __restrict__ bsum)
{
    __shared__ int sh[256];
    const int t = threadIdx.x;
    const int i = blockIdx.x * 256 + t;
    int v = (i < NNODES) ? deg[i] : 0;
    sh[t] = v;
    __syncthreads();
    for (int off = 1; off < 256; off <<= 1) {
        int u = (t >= off) ? sh[t - off] : 0;
        __syncthreads();
        sh[t] += u;
        __syncthreads();
    }
    if (i < NNODES) coff[i] = sh[t] - v;          // exclusive
    if (t == 255) bsum[blockIdx.x] = sh[255];
}

__global__ __launch_bounds__(256) void gat_scan2(int* __restrict__ bsum)
{
    __shared__ int sh[256];
    const int t = threadIdx.x;
    int v = (t < SCAN_BLOCKS) ? bsum[t] : 0;
    sh[t] = v;
    __syncthreads();
    for (int off = 1; off < 256; off <<= 1) {
        int u = (t >= off) ? sh[t - off] : 0;
        __syncthreads();
        sh[t] += u;
        __syncthreads();
    }
    if (t < SCAN_BLOCKS) bsum[t] = sh[t] - v;     // exclusive
}

__global__ __launch_bounds__(256) void gat_scan3(
    int* __restrict__ coff, const int* __restrict__ bsum)
{
    const int i = blockIdx.x * 256 + threadIdx.x;
    if (i < NNODES) coff[i] += bsum[blockIdx.x];
    if (i == 0) coff[NNODES] = NEDGES;
}

// ---------------------------------------------------------------------------
// Kernel 4: CSR fill — NO atomics. pos = coff[d] + rank[e].
// ---------------------------------------------------------------------------
__global__ __launch_bounds__(256) void gat_fill(
    const int* __restrict__ ei, const int* __restrict__ rank,
    const float* __restrict__ asrc, const float* __restrict__ adst,
    const int* __restrict__ coff,
    int* __restrict__ csr_src, float* __restrict__ csr_w)
{
    int e = blockIdx.x * 256 + threadIdx.x;
    int s = ei[e], d = ei[NEDGES + e];
    float4 a = *(const float4*)(asrc + s * 4);
    float4 b = *(const float4*)(adst + d * 4);
    float al;
    al = a.x + b.x; al = (al > 0.f) ? al : NEG * al; float e0 = __expf(al);
    al = a.y + b.y; al = (al > 0.f) ? al : NEG * al; float e1 = __expf(al);
    al = a.z + b.z; al = (al > 0.f) ? al : NEG * al; float e2 = __expf(al);
    al = a.w + b.w; al = (al > 0.f) ? al : NEG * al; float e3 = __expf(al);
    int pos = coff[d] + rank[e];
    csr_src[pos] = s;
    *(float4*)(csr_w + (size_t)pos * 4) = make_float4(e0, e1, e2, e3);
}

// ---------------------------------------------------------------------------
// Kernel 5: per-node — sum bucket weights, store ssum, normalize + gather
// h[src] + write out once. 32 lanes/node, 8 nodes/block. No fp atomics.
// ---------------------------------------------------------------------------
__global__ __launch_bounds__(256) void gat_node(
    const int* __restrict__ coff, const int* __restrict__ csr_src,
    const float* __restrict__ csr_w, const float* __restrict__ h,
    const float* __restrict__ bias, float* __restrict__ out,
    float* __restrict__ ssum)
{
    int t = threadIdx.x;
    int n = blockIdx.x * 8 + (t >> 5);
    int k = t & 31;
    int head = k >> 3;
    if (n >= NNODES) return;
    int beg = coff[n], end = coff[n + 1];

    float4 sum = make_float4(0.f, 0.f, 0.f, 0.f);
    for (int j = beg + k; j < end; j += 32) {
        float4 wv = *(const float4*)(csr_w + (size_t)j * 4);
        sum.x += wv.x; sum.y += wv.y; sum.z += wv.z; sum.w += wv.w;
    }
#pragma unroll
    for (int m = 16; m >= 1; m >>= 1) {
        sum.x += __shfl_xor(sum.x, m, 64);
        sum.y += __shfl_xor(sum.y, m, 64);
        sum.z += __shfl_xor(sum.z, m, 64);
        sum.w += __shfl_xor(sum.w, m, 64);
    }
    if (k == 0) *(float4*)(ssum + n * 4) = sum;
    float rs[4];
    rs[0] = 1.f / (sum.x + 1e-16f);
    rs[1] = 1.f / (sum.y + 1e-16f);
    rs[2] = 1.f / (sum.z + 1e-16f);
    rs[3] = 1.f / (sum.w + 1e-16f);
    const float rsel = rs[head];

    float4 acc = *(const float4*)(bias + k * 4);
    for (int j = beg; j < end; j++) {
        int s = csr_src[j];                               // broadcast load
        float w = csr_w[(size_t)j * 4 + head] * rsel;
        float4 hv = *(const float4*)(h + (size_t)s * HD + k * 4);
        acc.x = fmaf(hv.x, w, acc.x);
        acc.y = fmaf(hv.y, w, acc.y);
        acc.z = fmaf(hv.z, w, acc.z);
        acc.w = fmaf(hv.w, w, acc.w);
    }
    *(float4*)(out + (size_t)n * HD + k * 4) = acc;
}

// ---------------------------------------------------------------------------
// Kernel 6: alpha_pooled, edge-order (coalesced writes).
// ---------------------------------------------------------------------------
__global__ __launch_bounds__(256) void gat_apool(
    const int* __restrict__ ei, const float* __restrict__ asrc,
    const float* __restrict__ adst, const float* __restrict__ ssum,
    float* __restrict__ apool)
{
    int e = blockIdx.x * 256 + threadIdx.x;
    int s = ei[e], d = ei[NEDGES + e];
    float4 a  = *(const float4*)(asrc + s * 4);
    float4 b  = *(const float4*)(adst + d * 4);
    float4 sv = *(const float4*)(ssum + d * 4);
    float al;
    al = a.x + b.x; al = (al > 0.f) ? al : NEG * al; float w0 = __expf(al) / (sv.x + 1e-16f);
    al = a.y + b.y; al = (al > 0.f) ? al : NEG * al; float w1 = __expf(al) / (sv.y + 1e-16f);
    al = a.z + b.z; al = (al > 0.f) ? al : NEG * al; float w2 = __expf(al) / (sv.z + 1e-16f);
    al = a.w + b.w; al = (al > 0.f) ? al : NEG * al; float w3 = __expf(al) / (sv.w + 1e-16f);
    apool[e] = 0.25f * (w0 + w1 + w2 + w3);
}

// ---------------------------------------------------------------------------
extern "C" void kernel_launch(void* const* d_in, const int* in_sizes, int n_in,
                              void* d_out, int out_size, void* d_ws, size_t ws_size,
                              hipStream_t stream)
{
    const float* x       = (const float*)d_in[0];
    const int*   ei      = (const int*)d_in[1];
    const float* W       = (const float*)d_in[2];
    const float* att_src = (const float*)d_in[3];
    const float* att_dst = (const float*)d_in[4];
    const float* bias    = (const float*)d_in[5];

    float* out   = (float*)d_out;                    // (N,128)
    float* apool = out + (size_t)NNODES * HD;        // (E,)

    // workspace layout (all 16B-aligned chunks), ~48 MB total
    float* h      = (float*)d_ws;                    // N*128
    float* asrc   = h + (size_t)NNODES * HD;         // N*4
    float* adst   = asrc + NNODES * 4;               // N*4
    float* ssum   = adst + NNODES * 4;               // N*4
    float* csrw   = ssum + NNODES * 4;               // E*4
    int*   deg    = (int*)(csrw + (size_t)NEDGES * 4); // N
    int*   coff   = deg + NNODES;                    // N+1
    int*   rank   = coff + NNODES + 1;               // E
    int*   csrsrc = rank + NEDGES;                   // E
    int*   bsum   = csrsrc + NEDGES;                 // SCAN_BLOCKS

    hipMemsetAsync(deg, 0, (size_t)NNODES * sizeof(int), stream);

    gat_gemm<<<NNODES / 16, 256, 0, stream>>>(x, W, att_src, att_dst, h, asrc, adst);
    gat_deg<<<NEDGES / 256, 256, 0, stream>>>(ei, deg, rank);
    gat_scan1<<<SCAN_BLOCKS, 256, 0, stream>>>(deg, coff, bsum);
    gat_scan2<<<1, 256, 0, stream>>>(bsum);
    gat_scan3<<<SCAN_BLOCKS, 256, 0, stream>>>(coff, bsum);
    gat_fill<<<NEDGES / 256, 256, 0, stream>>>(ei, rank, asrc, adst, coff, csrsrc, csrw);
    gat_node<<<(NNODES + 7) / 8, 256, 0, stream>>>(coff, csrsrc, csrw, h, bias, out, ssum);
    gat_apool<<<NEDGES / 256, 256, 0, stream>>>(ei, asrc, adst, ssum, apool);
}

// Round 5
// 254.089 us; speedup vs baseline: 6.5680x; 1.2016x over previous
//
#include <hip/hip_runtime.h>

#define NNODES 50000
#define NEDGES 800000
#define HD 128            // HEADS*OUT_DIM
#define NEG 0.2f
#define SCAN_BLOCKS ((NNODES + 255) / 256)   // 196
#define MTILE 64
#define LDW 136           // bf16 row stride in LDS (row*4 mod 32 bank skew)

typedef __attribute__((ext_vector_type(8))) short short8;
typedef __attribute__((ext_vector_type(4))) float floatx4;

static __device__ inline unsigned short f2bf(float f) {
    unsigned u = __float_as_uint(f);
    return (unsigned short)((u + 0x7FFF + ((u >> 16) & 1)) >> 16);
}

// ---------------------------------------------------------------------------
// Kernel 1: h = x @ W^T via bf16 MFMA (16x16x32), fused asrc/adst dots.
// Block: 256 thr = 4 waves, 64 rows. x-tile + W cast to bf16 in LDS (ld=136).
// Wave w computes rows w*16..w*16+15 x all 128 cols (8 n-tiles).
// ---------------------------------------------------------------------------
__global__ __launch_bounds__(256) void gat_gemm(
    const float* __restrict__ x, const float* __restrict__ W,
    const float* __restrict__ att_src, const float* __restrict__ att_dst,
    float* __restrict__ h, float* __restrict__ asrc, float* __restrict__ adst)
{
    __shared__ unsigned short Wl[128 * LDW];
    __shared__ unsigned short xl[MTILE * LDW];
    const int t = threadIdx.x;
    const int rowBase = blockIdx.x * MTILE;

    // stage W (128x128 fp32 -> bf16)
    for (int idx = t * 4; idx < 128 * 128; idx += 1024) {
        int r = idx >> 7, c = idx & 127;
        float4 v = *(const float4*)(W + idx);
        ushort4 u;
        u.x = f2bf(v.x); u.y = f2bf(v.y); u.z = f2bf(v.z); u.w = f2bf(v.w);
        *(ushort4*)(Wl + r * LDW + c) = u;
    }
    // stage x tile (64x128 fp32 -> bf16), zero-fill past N
    for (int idx = t * 4; idx < MTILE * 128; idx += 1024) {
        int r = idx >> 7, c = idx & 127;
        int g = rowBase + r;
        float4 v = make_float4(0.f, 0.f, 0.f, 0.f);
        if (g < NNODES) v = *(const float4*)(x + (size_t)g * 128 + c);
        ushort4 u;
        u.x = f2bf(v.x); u.y = f2bf(v.y); u.z = f2bf(v.z); u.w = f2bf(v.w);
        *(ushort4*)(xl + r * LDW + c) = u;
    }
    __syncthreads();

    const int wave = t >> 6;
    const int lane = t & 63;
    const int c16  = lane & 15;   // n within tile / m for A-frag
    const int quad = lane >> 4;   // k-phase

    floatx4 acc[8];
#pragma unroll
    for (int nt = 0; nt < 8; nt++) acc[nt] = (floatx4)(0.f);

#pragma unroll
    for (int kc = 0; kc < 4; kc++) {
        short8 av = *(const short8*)(xl + (wave * 16 + c16) * LDW + kc * 32 + quad * 8);
#pragma unroll
        for (int nt = 0; nt < 8; nt++) {
            short8 bv = *(const short8*)(Wl + (nt * 16 + c16) * LDW + kc * 32 + quad * 8);
            acc[nt] = __builtin_amdgcn_mfma_f32_16x16x32_bf16(av, bv, acc[nt], 0, 0, 0);
        }
    }

    // preload attention vectors for this lane's columns
    float As[8], Ad[8];
#pragma unroll
    for (int nt = 0; nt < 8; nt++) {
        As[nt] = att_src[nt * 16 + c16];
        Ad[nt] = att_dst[nt * 16 + c16];
    }

    // epilogue: C layout col = c16 + 16*nt, row = quad*4 + r (within wave tile)
#pragma unroll
    for (int r = 0; r < 4; r++) {
        const int gr = rowBase + wave * 16 + quad * 4 + r;
        const bool ok = (gr < NNODES);
        if (ok) {
            float* hp = h + (size_t)gr * HD + c16;
#pragma unroll
            for (int nt = 0; nt < 8; nt++) hp[nt * 16] = acc[nt][r];
        }
#pragma unroll
        for (int hh = 0; hh < 4; hh++) {
            float ps = acc[2 * hh][r] * As[2 * hh] + acc[2 * hh + 1][r] * As[2 * hh + 1];
            float pd = acc[2 * hh][r] * Ad[2 * hh] + acc[2 * hh + 1][r] * Ad[2 * hh + 1];
#pragma unroll
            for (int m = 8; m >= 1; m >>= 1) {
                ps += __shfl_xor(ps, m, 64);
                pd += __shfl_xor(pd, m, 64);
            }
            if (c16 == 0 && ok) {
                asrc[gr * 4 + hh] = ps;
                adst[gr * 4 + hh] = pd;
            }
        }
    }
}

// ---------------------------------------------------------------------------
// Kernel 2: degree histogram. Returned old value = edge's in-bucket rank.
// ---------------------------------------------------------------------------
__global__ __launch_bounds__(256) void gat_deg(
    const int* __restrict__ ei, int* __restrict__ deg, int* __restrict__ rank)
{
    int e = blockIdx.x * 256 + threadIdx.x;
    int d = ei[NEDGES + e];
    rank[e] = atomicAdd(deg + d, 1);
}

// ---------------------------------------------------------------------------
// Hierarchical exclusive scan of deg -> coff.
// ---------------------------------------------------------------------------
__global__ __launch_bounds__(256) void gat_scan1(
    const int* __restrict__ deg, int* __restrict__ coff, int* __restrict__ bsum)
{
    __shared__ int sh[256];
    const int t = threadIdx.x;
    const int i = blockIdx.x * 256 + t;
    int v = (i < NNODES) ? deg[i] : 0;
    sh[t] = v;
    __syncthreads();
    for (int off = 1; off < 256; off <<= 1) {
        int u = (t >= off) ? sh[t - off] : 0;
        __syncthreads();
        sh[t] += u;
        __syncthreads();
    }
    if (i < NNODES) coff[i] = sh[t] - v;
    if (t == 255) bsum[blockIdx.x] = sh[255];
}

__global__ __launch_bounds__(256) void gat_scan2(int* __restrict__ bsum)
{
    __shared__ int sh[256];
    const int t = threadIdx.x;
    int v = (t < SCAN_BLOCKS) ? bsum[t] : 0;
    sh[t] = v;
    __syncthreads();
    for (int off = 1; off < 256; off <<= 1) {
        int u = (t >= off) ? sh[t - off] : 0;
        __syncthreads();
        sh[t] += u;
        __syncthreads();
    }
    if (t < SCAN_BLOCKS) bsum[t] = sh[t] - v;
}

__global__ __launch_bounds__(256) void gat_scan3(
    int* __restrict__ coff, const int* __restrict__ bsum)
{
    const int i = blockIdx.x * 256 + threadIdx.x;
    if (i < NNODES) coff[i] += bsum[blockIdx.x];
    if (i == 0) coff[NNODES] = NEDGES;
}

// ---------------------------------------------------------------------------
// Kernel 4: CSR fill — NO atomics. pos = coff[d] + rank[e].
// ---------------------------------------------------------------------------
__global__ __launch_bounds__(256) void gat_fill(
    const int* __restrict__ ei, const int* __restrict__ rank,
    const float* __restrict__ asrc, const float* __restrict__ adst,
    const int* __restrict__ coff,
    int* __restrict__ csr_src, float* __restrict__ csr_w)
{
    int e = blockIdx.x * 256 + threadIdx.x;
    int s = ei[e], d = ei[NEDGES + e];
    float4 a = *(const float4*)(asrc + s * 4);
    float4 b = *(const float4*)(adst + d * 4);
    float al;
    al = a.x + b.x; al = (al > 0.f) ? al : NEG * al; float e0 = __expf(al);
    al = a.y + b.y; al = (al > 0.f) ? al : NEG * al; float e1 = __expf(al);
    al = a.z + b.z; al = (al > 0.f) ? al : NEG * al; float e2 = __expf(al);
    al = a.w + b.w; al = (al > 0.f) ? al : NEG * al; float e3 = __expf(al);
    int pos = coff[d] + rank[e];
    csr_src[pos] = s;
    *(float4*)(csr_w + (size_t)pos * 4) = make_float4(e0, e1, e2, e3);
}

// ---------------------------------------------------------------------------
// Kernel 5: per-node — sum bucket weights, store ssum, normalize + gather
// h[src] + write out once. 32 lanes/node, 8 nodes/block. No fp atomics.
// ---------------------------------------------------------------------------
__global__ __launch_bounds__(256) void gat_node(
    const int* __restrict__ coff, const int* __restrict__ csr_src,
    const float* __restrict__ csr_w, const float* __restrict__ h,
    const float* __restrict__ bias, float* __restrict__ out,
    float* __restrict__ ssum)
{
    int t = threadIdx.x;
    int n = blockIdx.x * 8 + (t >> 5);
    int k = t & 31;
    int head = k >> 3;
    if (n >= NNODES) return;
    int beg = coff[n], end = coff[n + 1];

    float4 sum = make_float4(0.f, 0.f, 0.f, 0.f);
    for (int j = beg + k; j < end; j += 32) {
        float4 wv = *(const float4*)(csr_w + (size_t)j * 4);
        sum.x += wv.x; sum.y += wv.y; sum.z += wv.z; sum.w += wv.w;
    }
#pragma unroll
    for (int m = 16; m >= 1; m >>= 1) {
        sum.x += __shfl_xor(sum.x, m, 64);
        sum.y += __shfl_xor(sum.y, m, 64);
        sum.z += __shfl_xor(sum.z, m, 64);
        sum.w += __shfl_xor(sum.w, m, 64);
    }
    if (k == 0) *(float4*)(ssum + n * 4) = sum;
    float rs[4];
    rs[0] = 1.f / (sum.x + 1e-16f);
    rs[1] = 1.f / (sum.y + 1e-16f);
    rs[2] = 1.f / (sum.z + 1e-16f);
    rs[3] = 1.f / (sum.w + 1e-16f);
    const float rsel = rs[head];

    float4 acc = *(const float4*)(bias + k * 4);
    for (int j = beg; j < end; j++) {
        int s = csr_src[j];                               // broadcast load
        float w = csr_w[(size_t)j * 4 + head] * rsel;
        float4 hv = *(const float4*)(h + (size_t)s * HD + k * 4);
        acc.x = fmaf(hv.x, w, acc.x);
        acc.y = fmaf(hv.y, w, acc.y);
        acc.z = fmaf(hv.z, w, acc.z);
        acc.w = fmaf(hv.w, w, acc.w);
    }
    *(float4*)(out + (size_t)n * HD + k * 4) = acc;
}

// ---------------------------------------------------------------------------
// Kernel 6: alpha_pooled, edge-order (coalesced writes).
// ---------------------------------------------------------------------------
__global__ __launch_bounds__(256) void gat_apool(
    const int* __restrict__ ei, const float* __restrict__ asrc,
    const float* __restrict__ adst, const float* __restrict__ ssum,
    float* __restrict__ apool)
{
    int e = blockIdx.x * 256 + threadIdx.x;
    int s = ei[e], d = ei[NEDGES + e];
    float4 a  = *(const float4*)(asrc + s * 4);
    float4 b  = *(const float4*)(adst + d * 4);
    float4 sv = *(const float4*)(ssum + d * 4);
    float al;
    al = a.x + b.x; al = (al > 0.f) ? al : NEG * al; float w0 = __expf(al) / (sv.x + 1e-16f);
    al = a.y + b.y; al = (al > 0.f) ? al : NEG * al; float w1 = __expf(al) / (sv.y + 1e-16f);
    al = a.z + b.z; al = (al > 0.f) ? al : NEG * al; float w2 = __expf(al) / (sv.z + 1e-16f);
    al = a.w + b.w; al = (al > 0.f) ? al : NEG * al; float w3 = __expf(al) / (sv.w + 1e-16f);
    apool[e] = 0.25f * (w0 + w1 + w2 + w3);
}

// ---------------------------------------------------------------------------
extern "C" void kernel_launch(void* const* d_in, const int* in_sizes, int n_in,
                              void* d_out, int out_size, void* d_ws, size_t ws_size,
                              hipStream_t stream)
{
    const float* x       = (const float*)d_in[0];
    const int*   ei      = (const int*)d_in[1];
    const float* W       = (const float*)d_in[2];
    const float* att_src = (const float*)d_in[3];
    const float* att_dst = (const float*)d_in[4];
    const float* bias    = (const float*)d_in[5];

    float* out   = (float*)d_out;                    // (N,128)
    float* apool = out + (size_t)NNODES * HD;        // (E,)

    // workspace layout (all 16B-aligned chunks), ~48 MB total
    float* h      = (float*)d_ws;                    // N*128
    float* asrc   = h + (size_t)NNODES * HD;         // N*4
    float* adst   = asrc + NNODES * 4;               // N*4
    float* ssum   = adst + NNODES * 4;               // N*4
    float* csrw   = ssum + NNODES * 4;               // E*4
    int*   deg    = (int*)(csrw + (size_t)NEDGES * 4); // N
    int*   coff   = deg + NNODES;                    // N+1
    int*   rank   = coff + NNODES + 1;               // E
    int*   csrsrc = rank + NEDGES;                   // E
    int*   bsum   = csrsrc + NEDGES;                 // SCAN_BLOCKS

    hipMemsetAsync(deg, 0, (size_t)NNODES * sizeof(int), stream);

    gat_gemm<<<(NNODES + MTILE - 1) / MTILE, 256, 0, stream>>>(
        x, W, att_src, att_dst, h, asrc, adst);
    gat_deg<<<NEDGES / 256, 256, 0, stream>>>(ei, deg, rank);
    gat_scan1<<<SCAN_BLOCKS, 256, 0, stream>>>(deg, coff, bsum);
    gat_scan2<<<1, 256, 0, stream>>>(bsum);
    gat_scan3<<<SCAN_BLOCKS, 256, 0, stream>>>(coff, bsum);
    gat_fill<<<NEDGES / 256, 256, 0, stream>>>(ei, rank, asrc, adst, coff, csrsrc, csrw);
    gat_node<<<(NNODES + 7) / 8, 256, 0, stream>>>(coff, csrsrc, csrw, h, bias, out, ssum);
    gat_apool<<<NEDGES / 256, 256, 0, stream>>>(ei, asrc, adst, ssum, apool);
}

// Round 6
// 231.115 us; speedup vs baseline: 7.2209x; 1.0994x over previous
//
#include <hip/hip_runtime.h>

#define NNODES 50000
#define NEDGES 800000
#define HD 128            // HEADS*OUT_DIM
#define NEG 0.2f
#define SCAN_BLOCKS ((NNODES + 255) / 256)   // 196
#define MTILE 64
#define LDW 136           // bf16 row stride in LDS

typedef __attribute__((ext_vector_type(8))) short short8;
typedef __attribute__((ext_vector_type(4))) float floatx4;

static __device__ inline unsigned short f2bf(float f) {
    unsigned u = __float_as_uint(f);
    return (unsigned short)((u + 0x7FFF + ((u >> 16) & 1)) >> 16);
}
static __device__ inline float bf2f(unsigned short u) {
    return __uint_as_float(((unsigned)u) << 16);
}

// ---------------------------------------------------------------------------
// Kernel 1: h(bf16) = x @ W^T via bf16 MFMA (16x16x32), fused asrc/adst dots.
// Block: 256 thr = 4 waves, 64 rows. x-tile + W cast to bf16 in LDS (ld=136).
// ---------------------------------------------------------------------------
__global__ __launch_bounds__(256) void gat_gemm(
    const float* __restrict__ x, const float* __restrict__ W,
    const float* __restrict__ att_src, const float* __restrict__ att_dst,
    unsigned short* __restrict__ h, float* __restrict__ asrc,
    float* __restrict__ adst)
{
    __shared__ unsigned short Wl[128 * LDW];
    __shared__ unsigned short xl[MTILE * LDW];
    const int t = threadIdx.x;
    const int rowBase = blockIdx.x * MTILE;

    for (int idx = t * 4; idx < 128 * 128; idx += 1024) {
        int r = idx >> 7, c = idx & 127;
        float4 v = *(const float4*)(W + idx);
        ushort4 u;
        u.x = f2bf(v.x); u.y = f2bf(v.y); u.z = f2bf(v.z); u.w = f2bf(v.w);
        *(ushort4*)(Wl + r * LDW + c) = u;
    }
    for (int idx = t * 4; idx < MTILE * 128; idx += 1024) {
        int r = idx >> 7, c = idx & 127;
        int g = rowBase + r;
        float4 v = make_float4(0.f, 0.f, 0.f, 0.f);
        if (g < NNODES) v = *(const float4*)(x + (size_t)g * 128 + c);
        ushort4 u;
        u.x = f2bf(v.x); u.y = f2bf(v.y); u.z = f2bf(v.z); u.w = f2bf(v.w);
        *(ushort4*)(xl + r * LDW + c) = u;
    }
    __syncthreads();

    const int wave = t >> 6;
    const int lane = t & 63;
    const int c16  = lane & 15;
    const int quad = lane >> 4;

    floatx4 acc[8];
#pragma unroll
    for (int nt = 0; nt < 8; nt++) acc[nt] = (floatx4)(0.f);

#pragma unroll
    for (int kc = 0; kc < 4; kc++) {
        short8 av = *(const short8*)(xl + (wave * 16 + c16) * LDW + kc * 32 + quad * 8);
#pragma unroll
        for (int nt = 0; nt < 8; nt++) {
            short8 bv = *(const short8*)(Wl + (nt * 16 + c16) * LDW + kc * 32 + quad * 8);
            acc[nt] = __builtin_amdgcn_mfma_f32_16x16x32_bf16(av, bv, acc[nt], 0, 0, 0);
        }
    }

    float As[8], Ad[8];
#pragma unroll
    for (int nt = 0; nt < 8; nt++) {
        As[nt] = att_src[nt * 16 + c16];
        Ad[nt] = att_dst[nt * 16 + c16];
    }

#pragma unroll
    for (int r = 0; r < 4; r++) {
        const int gr = rowBase + wave * 16 + quad * 4 + r;
        const bool ok = (gr < NNODES);
        if (ok) {
            unsigned short* hp = h + (size_t)gr * HD + c16;
#pragma unroll
            for (int nt = 0; nt < 8; nt++) hp[nt * 16] = f2bf(acc[nt][r]);
        }
#pragma unroll
        for (int hh = 0; hh < 4; hh++) {
            float ps = acc[2 * hh][r] * As[2 * hh] + acc[2 * hh + 1][r] * As[2 * hh + 1];
            float pd = acc[2 * hh][r] * Ad[2 * hh] + acc[2 * hh + 1][r] * Ad[2 * hh + 1];
#pragma unroll
            for (int m = 8; m >= 1; m >>= 1) {
                ps += __shfl_xor(ps, m, 64);
                pd += __shfl_xor(pd, m, 64);
            }
            if (c16 == 0 && ok) {
                asrc[gr * 4 + hh] = ps;
                adst[gr * 4 + hh] = pd;
            }
        }
    }
}

// ---------------------------------------------------------------------------
// Kernel 2: degree histogram. Returned old value = edge's in-bucket rank.
// ---------------------------------------------------------------------------
__global__ __launch_bounds__(256) void gat_deg(
    const int* __restrict__ ei, int* __restrict__ deg, int* __restrict__ rank)
{
    int e = blockIdx.x * 256 + threadIdx.x;
    int d = ei[NEDGES + e];
    rank[e] = atomicAdd(deg + d, 1);
}

// ---------------------------------------------------------------------------
// Hierarchical exclusive scan of deg -> coff.
// ---------------------------------------------------------------------------
__global__ __launch_bounds__(256) void gat_scan1(
    const int* __restrict__ deg, int* __restrict__ coff, int* __restrict__ bsum)
{
    __shared__ int sh[256];
    const int t = threadIdx.x;
    const int i = blockIdx.x * 256 + t;
    int v = (i < NNODES) ? deg[i] : 0;
    sh[t] = v;
    __syncthreads();
    for (int off = 1; off < 256; off <<= 1) {
        int u = (t >= off) ? sh[t - off] : 0;
        __syncthreads();
        sh[t] += u;
        __syncthreads();
    }
    if (i < NNODES) coff[i] = sh[t] - v;
    if (t == 255) bsum[blockIdx.x] = sh[255];
}

__global__ __launch_bounds__(256) void gat_scan2(int* __restrict__ bsum)
{
    __shared__ int sh[256];
    const int t = threadIdx.x;
    int v = (t < SCAN_BLOCKS) ? bsum[t] : 0;
    sh[t] = v;
    __syncthreads();
    for (int off = 1; off < 256; off <<= 1) {
        int u = (t >= off) ? sh[t - off] : 0;
        __syncthreads();
        sh[t] += u;
        __syncthreads();
    }
    if (t < SCAN_BLOCKS) bsum[t] = sh[t] - v;
}

__global__ __launch_bounds__(256) void gat_scan3(
    int* __restrict__ coff, const int* __restrict__ bsum)
{
    const int i = blockIdx.x * 256 + threadIdx.x;
    if (i < NNODES) coff[i] += bsum[blockIdx.x];
    if (i == 0) coff[NNODES] = NEDGES;
}

// ---------------------------------------------------------------------------
// Kernel 4: CSR fill — NO atomics. pos = coff[d] + rank[e].
// ---------------------------------------------------------------------------
__global__ __launch_bounds__(256) void gat_fill(
    const int* __restrict__ ei, const int* __restrict__ rank,
    const float* __restrict__ asrc, const float* __restrict__ adst,
    const int* __restrict__ coff,
    int* __restrict__ csr_src, float* __restrict__ csr_w)
{
    int e = blockIdx.x * 256 + threadIdx.x;
    int s = ei[e], d = ei[NEDGES + e];
    float4 a = *(const float4*)(asrc + s * 4);
    float4 b = *(const float4*)(adst + d * 4);
    float al;
    al = a.x + b.x; al = (al > 0.f) ? al : NEG * al; float e0 = __expf(al);
    al = a.y + b.y; al = (al > 0.f) ? al : NEG * al; float e1 = __expf(al);
    al = a.z + b.z; al = (al > 0.f) ? al : NEG * al; float e2 = __expf(al);
    al = a.w + b.w; al = (al > 0.f) ? al : NEG * al; float e3 = __expf(al);
    int pos = coff[d] + rank[e];
    csr_src[pos] = s;
    *(float4*)(csr_w + (size_t)pos * 4) = make_float4(e0, e1, e2, e3);
}

// ---------------------------------------------------------------------------
// Kernel 5: per-node — sum bucket weights, store ssum, normalize + gather
// bf16 h[src] + write out once. 32 lanes/node, 8 nodes/block. 2-way unroll.
// ---------------------------------------------------------------------------
__global__ __launch_bounds__(256) void gat_node(
    const int* __restrict__ coff, const int* __restrict__ csr_src,
    const float* __restrict__ csr_w, const unsigned short* __restrict__ h,
    const float* __restrict__ bias, float* __restrict__ out,
    float* __restrict__ ssum)
{
    int t = threadIdx.x;
    int n = blockIdx.x * 8 + (t >> 5);
    int k = t & 31;
    int head = k >> 3;
    if (n >= NNODES) return;
    int beg = coff[n], end = coff[n + 1];

    float4 sum = make_float4(0.f, 0.f, 0.f, 0.f);
    for (int j = beg + k; j < end; j += 32) {
        float4 wv = *(const float4*)(csr_w + (size_t)j * 4);
        sum.x += wv.x; sum.y += wv.y; sum.z += wv.z; sum.w += wv.w;
    }
#pragma unroll
    for (int m = 16; m >= 1; m >>= 1) {
        sum.x += __shfl_xor(sum.x, m, 64);
        sum.y += __shfl_xor(sum.y, m, 64);
        sum.z += __shfl_xor(sum.z, m, 64);
        sum.w += __shfl_xor(sum.w, m, 64);
    }
    if (k == 0) *(float4*)(ssum + n * 4) = sum;
    float rs[4];
    rs[0] = 1.f / (sum.x + 1e-16f);
    rs[1] = 1.f / (sum.y + 1e-16f);
    rs[2] = 1.f / (sum.z + 1e-16f);
    rs[3] = 1.f / (sum.w + 1e-16f);
    const float rsel = rs[head];

    float4 acc = *(const float4*)(bias + k * 4);
    float4 acc2 = make_float4(0.f, 0.f, 0.f, 0.f);
    int j = beg;
    for (; j + 2 <= end; j += 2) {
        int s0 = csr_src[j];
        int s1 = csr_src[j + 1];
        float w0 = csr_w[(size_t)j * 4 + head] * rsel;
        float w1 = csr_w[(size_t)(j + 1) * 4 + head] * rsel;
        ushort4 u0 = *(const ushort4*)(h + (size_t)s0 * HD + k * 4);
        ushort4 u1 = *(const ushort4*)(h + (size_t)s1 * HD + k * 4);
        acc.x  = fmaf(bf2f(u0.x), w0, acc.x);
        acc.y  = fmaf(bf2f(u0.y), w0, acc.y);
        acc.z  = fmaf(bf2f(u0.z), w0, acc.z);
        acc.w  = fmaf(bf2f(u0.w), w0, acc.w);
        acc2.x = fmaf(bf2f(u1.x), w1, acc2.x);
        acc2.y = fmaf(bf2f(u1.y), w1, acc2.y);
        acc2.z = fmaf(bf2f(u1.z), w1, acc2.z);
        acc2.w = fmaf(bf2f(u1.w), w1, acc2.w);
    }
    if (j < end) {
        int s0 = csr_src[j];
        float w0 = csr_w[(size_t)j * 4 + head] * rsel;
        ushort4 u0 = *(const ushort4*)(h + (size_t)s0 * HD + k * 4);
        acc.x = fmaf(bf2f(u0.x), w0, acc.x);
        acc.y = fmaf(bf2f(u0.y), w0, acc.y);
        acc.z = fmaf(bf2f(u0.z), w0, acc.z);
        acc.w = fmaf(bf2f(u0.w), w0, acc.w);
    }
    acc.x += acc2.x; acc.y += acc2.y; acc.z += acc2.z; acc.w += acc2.w;
    *(float4*)(out + (size_t)n * HD + k * 4) = acc;
}

// ---------------------------------------------------------------------------
// Kernel 6: alpha_pooled from precomputed csr_w + ssum (one fewer gather,
// no exp recompute).
// ---------------------------------------------------------------------------
__global__ __launch_bounds__(256) void gat_apool(
    const int* __restrict__ ei, const int* __restrict__ rank,
    const int* __restrict__ coff, const float* __restrict__ csr_w,
    const float* __restrict__ ssum, float* __restrict__ apool)
{
    int e = blockIdx.x * 256 + threadIdx.x;
    int d = ei[NEDGES + e];
    int pos = coff[d] + rank[e];
    float4 wv = *(const float4*)(csr_w + (size_t)pos * 4);
    float4 sv = *(const float4*)(ssum + d * 4);
    apool[e] = 0.25f * (wv.x / (sv.x + 1e-16f) + wv.y / (sv.y + 1e-16f) +
                        wv.z / (sv.z + 1e-16f) + wv.w / (sv.w + 1e-16f));
}

// ---------------------------------------------------------------------------
extern "C" void kernel_launch(void* const* d_in, const int* in_sizes, int n_in,
                              void* d_out, int out_size, void* d_ws, size_t ws_size,
                              hipStream_t stream)
{
    const float* x       = (const float*)d_in[0];
    const int*   ei      = (const int*)d_in[1];
    const float* W       = (const float*)d_in[2];
    const float* att_src = (const float*)d_in[3];
    const float* att_dst = (const float*)d_in[4];
    const float* bias    = (const float*)d_in[5];

    float* out   = (float*)d_out;                    // (N,128)
    float* apool = out + (size_t)NNODES * HD;        // (E,)

    // workspace layout (16B-aligned chunks)
    unsigned short* h = (unsigned short*)d_ws;            // N*128 bf16
    float* asrc   = (float*)(h + (size_t)NNODES * HD);    // N*4
    float* adst   = asrc + NNODES * 4;               // N*4
    float* ssum   = adst + NNODES * 4;               // N*4
    float* csrw   = ssum + NNODES * 4;               // E*4
    int*   deg    = (int*)(csrw + (size_t)NEDGES * 4); // N
    int*   coff   = deg + NNODES;                    // N+1
    int*   rank   = coff + NNODES + 1;               // E
    int*   csrsrc = rank + NEDGES;                   // E
    int*   bsum   = csrsrc + NEDGES;                 // SCAN_BLOCKS

    hipMemsetAsync(deg, 0, (size_t)NNODES * sizeof(int), stream);

    gat_gemm<<<(NNODES + MTILE - 1) / MTILE, 256, 0, stream>>>(
        x, W, att_src, att_dst, h, asrc, adst);
    gat_deg<<<NEDGES / 256, 256, 0, stream>>>(ei, deg, rank);
    gat_scan1<<<SCAN_BLOCKS, 256, 0, stream>>>(deg, coff, bsum);
    gat_scan2<<<1, 256, 0, stream>>>(bsum);
    gat_scan3<<<SCAN_BLOCKS, 256, 0, stream>>>(coff, bsum);
    gat_fill<<<NEDGES / 256, 256, 0, stream>>>(ei, rank, asrc, adst, coff, csrsrc, csrw);
    gat_node<<<(NNODES + 7) / 8, 256, 0, stream>>>(coff, csrsrc, csrw, h, bias, out, ssum);
    gat_apool<<<NEDGES / 256, 256, 0, stream>>>(ei, rank, coff, csrw, ssum, apool);
}

// Round 7
// 230.632 us; speedup vs baseline: 7.2360x; 1.0021x over previous
//
#include <hip/hip_runtime.h>

#define NNODES 50000
#define NEDGES 800000
#define HD 128            // HEADS*OUT_DIM
#define NEG 0.2f
#define SCAN_BLOCKS ((NNODES + 255) / 256)   // 196
#define MTILE 64
#define LDW 136           // bf16 row stride in LDS

typedef __attribute__((ext_vector_type(8))) short short8;
typedef __attribute__((ext_vector_type(4))) float floatx4;

static __device__ inline unsigned short f2bf(float f) {
    unsigned u = __float_as_uint(f);
    return (unsigned short)((u + 0x7FFF + ((u >> 16) & 1)) >> 16);
}
static __device__ inline float bf2f(unsigned short u) {
    return __uint_as_float(((unsigned)u) << 16);
}

// ---------------------------------------------------------------------------
// Kernel 0: one-shot W fp32 -> bf16 (16K elements). Removes the 782x
// redundant per-block conversion from gat_gemm.
// ---------------------------------------------------------------------------
__global__ __launch_bounds__(256) void gat_wprep(
    const float* __restrict__ W, unsigned short* __restrict__ Wbf)
{
    int i = (blockIdx.x * 256 + threadIdx.x) * 4;   // 16 blocks
    float4 v = *(const float4*)(W + i);
    ushort4 u;
    u.x = f2bf(v.x); u.y = f2bf(v.y); u.z = f2bf(v.z); u.w = f2bf(v.w);
    *(ushort4*)(Wbf + i) = u;
}

// ---------------------------------------------------------------------------
// Kernel 1: h(bf16) = x @ W^T via bf16 MFMA (16x16x32), fused asrc/adst dots.
// Block: 256 thr = 4 waves, 64 rows. Wbf staged as-is (16B copies, no cvt).
// ---------------------------------------------------------------------------
__global__ __launch_bounds__(256) void gat_gemm(
    const float* __restrict__ x, const unsigned short* __restrict__ Wbf,
    const float* __restrict__ att_src, const float* __restrict__ att_dst,
    unsigned short* __restrict__ h, float* __restrict__ asrc,
    float* __restrict__ adst)
{
    __shared__ unsigned short Wl[128 * LDW];
    __shared__ unsigned short xl[MTILE * LDW];
    const int t = threadIdx.x;
    const int rowBase = blockIdx.x * MTILE;

    // stage pre-converted W: 16384 bf16, 16 B per thread per iter (8 iters)
    for (int idx = t * 8; idx < 128 * 128; idx += 2048) {
        int r = idx >> 7, c = idx & 127;
        *(short8*)(Wl + r * LDW + c) = *(const short8*)(Wbf + idx);
    }
    // stage x tile (64x128 fp32 -> bf16), zero-fill past N
    for (int idx = t * 4; idx < MTILE * 128; idx += 1024) {
        int r = idx >> 7, c = idx & 127;
        int g = rowBase + r;
        float4 v = make_float4(0.f, 0.f, 0.f, 0.f);
        if (g < NNODES) v = *(const float4*)(x + (size_t)g * 128 + c);
        ushort4 u;
        u.x = f2bf(v.x); u.y = f2bf(v.y); u.z = f2bf(v.z); u.w = f2bf(v.w);
        *(ushort4*)(xl + r * LDW + c) = u;
    }
    __syncthreads();

    const int wave = t >> 6;
    const int lane = t & 63;
    const int c16  = lane & 15;
    const int quad = lane >> 4;

    floatx4 acc[8];
#pragma unroll
    for (int nt = 0; nt < 8; nt++) acc[nt] = (floatx4)(0.f);

#pragma unroll
    for (int kc = 0; kc < 4; kc++) {
        short8 av = *(const short8*)(xl + (wave * 16 + c16) * LDW + kc * 32 + quad * 8);
#pragma unroll
        for (int nt = 0; nt < 8; nt++) {
            short8 bv = *(const short8*)(Wl + (nt * 16 + c16) * LDW + kc * 32 + quad * 8);
            acc[nt] = __builtin_amdgcn_mfma_f32_16x16x32_bf16(av, bv, acc[nt], 0, 0, 0);
        }
    }

    float As[8], Ad[8];
#pragma unroll
    for (int nt = 0; nt < 8; nt++) {
        As[nt] = att_src[nt * 16 + c16];
        Ad[nt] = att_dst[nt * 16 + c16];
    }

#pragma unroll
    for (int r = 0; r < 4; r++) {
        const int gr = rowBase + wave * 16 + quad * 4 + r;
        const bool ok = (gr < NNODES);
        if (ok) {
            unsigned short* hp = h + (size_t)gr * HD + c16;
#pragma unroll
            for (int nt = 0; nt < 8; nt++) hp[nt * 16] = f2bf(acc[nt][r]);
        }
#pragma unroll
        for (int hh = 0; hh < 4; hh++) {
            float ps = acc[2 * hh][r] * As[2 * hh] + acc[2 * hh + 1][r] * As[2 * hh + 1];
            float pd = acc[2 * hh][r] * Ad[2 * hh] + acc[2 * hh + 1][r] * Ad[2 * hh + 1];
#pragma unroll
            for (int m = 8; m >= 1; m >>= 1) {
                ps += __shfl_xor(ps, m, 64);
                pd += __shfl_xor(pd, m, 64);
            }
            if (c16 == 0 && ok) {
                asrc[gr * 4 + hh] = ps;
                adst[gr * 4 + hh] = pd;
            }
        }
    }
}

// ---------------------------------------------------------------------------
// Kernel 2: degree histogram. Returned old value = edge's in-bucket rank.
// ---------------------------------------------------------------------------
__global__ __launch_bounds__(256) void gat_deg(
    const int* __restrict__ ei, int* __restrict__ deg, int* __restrict__ rank)
{
    int e = blockIdx.x * 256 + threadIdx.x;
    int d = ei[NEDGES + e];
    rank[e] = atomicAdd(deg + d, 1);
}

// ---------------------------------------------------------------------------
// Hierarchical exclusive scan of deg -> coff.
// ---------------------------------------------------------------------------
__global__ __launch_bounds__(256) void gat_scan1(
    const int* __restrict__ deg, int* __restrict__ coff, int* __restrict__ bsum)
{
    __shared__ int sh[256];
    const int t = threadIdx.x;
    const int i = blockIdx.x * 256 + t;
    int v = (i < NNODES) ? deg[i] : 0;
    sh[t] = v;
    __syncthreads();
    for (int off = 1; off < 256; off <<= 1) {
        int u = (t >= off) ? sh[t - off] : 0;
        __syncthreads();
        sh[t] += u;
        __syncthreads();
    }
    if (i < NNODES) coff[i] = sh[t] - v;
    if (t == 255) bsum[blockIdx.x] = sh[255];
}

__global__ __launch_bounds__(256) void gat_scan2(int* __restrict__ bsum)
{
    __shared__ int sh[256];
    const int t = threadIdx.x;
    int v = (t < SCAN_BLOCKS) ? bsum[t] : 0;
    sh[t] = v;
    __syncthreads();
    for (int off = 1; off < 256; off <<= 1) {
        int u = (t >= off) ? sh[t - off] : 0;
        __syncthreads();
        sh[t] += u;
        __syncthreads();
    }
    if (t < SCAN_BLOCKS) bsum[t] = sh[t] - v;
}

__global__ __launch_bounds__(256) void gat_scan3(
    int* __restrict__ coff, const int* __restrict__ bsum)
{
    const int i = blockIdx.x * 256 + threadIdx.x;
    if (i < NNODES) coff[i] += bsum[blockIdx.x];
    if (i == 0) coff[NNODES] = NEDGES;
}

// ---------------------------------------------------------------------------
// Kernel 4: CSR fill — NO atomics. pos = coff[d] + rank[e].
// ---------------------------------------------------------------------------
__global__ __launch_bounds__(256) void gat_fill(
    const int* __restrict__ ei, const int* __restrict__ rank,
    const float* __restrict__ asrc, const float* __restrict__ adst,
    const int* __restrict__ coff,
    int* __restrict__ csr_src, float* __restrict__ csr_w)
{
    int e = blockIdx.x * 256 + threadIdx.x;
    int s = ei[e], d = ei[NEDGES + e];
    float4 a = *(const float4*)(asrc + s * 4);
    float4 b = *(const float4*)(adst + d * 4);
    float al;
    al = a.x + b.x; al = (al > 0.f) ? al : NEG * al; float e0 = __expf(al);
    al = a.y + b.y; al = (al > 0.f) ? al : NEG * al; float e1 = __expf(al);
    al = a.z + b.z; al = (al > 0.f) ? al : NEG * al; float e2 = __expf(al);
    al = a.w + b.w; al = (al > 0.f) ? al : NEG * al; float e3 = __expf(al);
    int pos = coff[d] + rank[e];
    csr_src[pos] = s;
    *(float4*)(csr_w + (size_t)pos * 4) = make_float4(e0, e1, e2, e3);
}

// ---------------------------------------------------------------------------
// Kernel 5: per-node — sum bucket weights, store ssum, normalize + gather
// bf16 h[src] + write out once. 32 lanes/node, 8 nodes/block. 2-way unroll.
// ---------------------------------------------------------------------------
__global__ __launch_bounds__(256) void gat_node(
    const int* __restrict__ coff, const int* __restrict__ csr_src,
    const float* __restrict__ csr_w, const unsigned short* __restrict__ h,
    const float* __restrict__ bias, float* __restrict__ out,
    float* __restrict__ ssum)
{
    int t = threadIdx.x;
    int n = blockIdx.x * 8 + (t >> 5);
    int k = t & 31;
    int head = k >> 3;
    if (n >= NNODES) return;
    int beg = coff[n], end = coff[n + 1];

    float4 sum = make_float4(0.f, 0.f, 0.f, 0.f);
    for (int j = beg + k; j < end; j += 32) {
        float4 wv = *(const float4*)(csr_w + (size_t)j * 4);
        sum.x += wv.x; sum.y += wv.y; sum.z += wv.z; sum.w += wv.w;
    }
#pragma unroll
    for (int m = 16; m >= 1; m >>= 1) {
        sum.x += __shfl_xor(sum.x, m, 64);
        sum.y += __shfl_xor(sum.y, m, 64);
        sum.z += __shfl_xor(sum.z, m, 64);
        sum.w += __shfl_xor(sum.w, m, 64);
    }
    if (k == 0) *(float4*)(ssum + n * 4) = sum;
    float rs[4];
    rs[0] = 1.f / (sum.x + 1e-16f);
    rs[1] = 1.f / (sum.y + 1e-16f);
    rs[2] = 1.f / (sum.z + 1e-16f);
    rs[3] = 1.f / (sum.w + 1e-16f);
    const float rsel = rs[head];

    float4 acc = *(const float4*)(bias + k * 4);
    float4 acc2 = make_float4(0.f, 0.f, 0.f, 0.f);
    int j = beg;
    for (; j + 2 <= end; j += 2) {
        int s0 = csr_src[j];
        int s1 = csr_src[j + 1];
        float w0 = csr_w[(size_t)j * 4 + head] * rsel;
        float w1 = csr_w[(size_t)(j + 1) * 4 + head] * rsel;
        ushort4 u0 = *(const ushort4*)(h + (size_t)s0 * HD + k * 4);
        ushort4 u1 = *(const ushort4*)(h + (size_t)s1 * HD + k * 4);
        acc.x  = fmaf(bf2f(u0.x), w0, acc.x);
        acc.y  = fmaf(bf2f(u0.y), w0, acc.y);
        acc.z  = fmaf(bf2f(u0.z), w0, acc.z);
        acc.w  = fmaf(bf2f(u0.w), w0, acc.w);
        acc2.x = fmaf(bf2f(u1.x), w1, acc2.x);
        acc2.y = fmaf(bf2f(u1.y), w1, acc2.y);
        acc2.z = fmaf(bf2f(u1.z), w1, acc2.z);
        acc2.w = fmaf(bf2f(u1.w), w1, acc2.w);
    }
    if (j < end) {
        int s0 = csr_src[j];
        float w0 = csr_w[(size_t)j * 4 + head] * rsel;
        ushort4 u0 = *(const ushort4*)(h + (size_t)s0 * HD + k * 4);
        acc.x = fmaf(bf2f(u0.x), w0, acc.x);
        acc.y = fmaf(bf2f(u0.y), w0, acc.y);
        acc.z = fmaf(bf2f(u0.z), w0, acc.z);
        acc.w = fmaf(bf2f(u0.w), w0, acc.w);
    }
    acc.x += acc2.x; acc.y += acc2.y; acc.z += acc2.z; acc.w += acc2.w;
    *(float4*)(out + (size_t)n * HD + k * 4) = acc;
}

// ---------------------------------------------------------------------------
// Kernel 6: alpha_pooled from precomputed csr_w + ssum.
// ---------------------------------------------------------------------------
__global__ __launch_bounds__(256) void gat_apool(
    const int* __restrict__ ei, const int* __restrict__ rank,
    const int* __restrict__ coff, const float* __restrict__ csr_w,
    const float* __restrict__ ssum, float* __restrict__ apool)
{
    int e = blockIdx.x * 256 + threadIdx.x;
    int d = ei[NEDGES + e];
    int pos = coff[d] + rank[e];
    float4 wv = *(const float4*)(csr_w + (size_t)pos * 4);
    float4 sv = *(const float4*)(ssum + d * 4);
    apool[e] = 0.25f * (wv.x / (sv.x + 1e-16f) + wv.y / (sv.y + 1e-16f) +
                        wv.z / (sv.z + 1e-16f) + wv.w / (sv.w + 1e-16f));
}

// ---------------------------------------------------------------------------
extern "C" void kernel_launch(void* const* d_in, const int* in_sizes, int n_in,
                              void* d_out, int out_size, void* d_ws, size_t ws_size,
                              hipStream_t stream)
{
    const float* x       = (const float*)d_in[0];
    const int*   ei      = (const int*)d_in[1];
    const float* W       = (const float*)d_in[2];
    const float* att_src = (const float*)d_in[3];
    const float* att_dst = (const float*)d_in[4];
    const float* bias    = (const float*)d_in[5];

    float* out   = (float*)d_out;                    // (N,128)
    float* apool = out + (size_t)NNODES * HD;        // (E,)

    // workspace layout (16B-aligned chunks)
    unsigned short* h = (unsigned short*)d_ws;            // N*128 bf16
    float* asrc   = (float*)(h + (size_t)NNODES * HD);    // N*4
    float* adst   = asrc + NNODES * 4;               // N*4
    float* ssum   = adst + NNODES * 4;               // N*4
    float* csrw   = ssum + NNODES * 4;               // E*4
    int*   deg    = (int*)(csrw + (size_t)NEDGES * 4); // N
    int*   coff   = deg + NNODES;                    // N+1
    int*   rank   = coff + NNODES + 1;               // E
    int*   csrsrc = rank + NEDGES;                   // E
    int*   bsum   = csrsrc + NEDGES;                 // SCAN_BLOCKS
    unsigned short* wbf = (unsigned short*)(bsum + SCAN_BLOCKS + 2); // 16384

    hipMemsetAsync(deg, 0, (size_t)NNODES * sizeof(int), stream);

    gat_wprep<<<16, 256, 0, stream>>>(W, wbf);
    gat_gemm<<<(NNODES + MTILE - 1) / MTILE, 256, 0, stream>>>(
        x, wbf, att_src, att_dst, h, asrc, adst);
    gat_deg<<<NEDGES / 256, 256, 0, stream>>>(ei, deg, rank);
    gat_scan1<<<SCAN_BLOCKS, 256, 0, stream>>>(deg, coff, bsum);
    gat_scan2<<<1, 256, 0, stream>>>(bsum);
    gat_scan3<<<SCAN_BLOCKS, 256, 0, stream>>>(coff, bsum);
    gat_fill<<<NEDGES / 256, 256, 0, stream>>>(ei, rank, asrc, adst, coff, csrsrc, csrw);
    gat_node<<<(NNODES + 7) / 8, 256, 0, stream>>>(coff, csrsrc, csrw, h, bias, out, ssum);
    gat_apool<<<NEDGES / 256, 256, 0, stream>>>(ei, rank, coff, csrw, ssum, apool);
}

// Round 8
// 224.365 us; speedup vs baseline: 7.4381x; 1.0279x over previous
//
#include <hip/hip_runtime.h>

#define NNODES 50000
#define NEDGES 800000
#define HD 128            // HEADS*OUT_DIM
#define NEG 0.2f
#define SCAN_BLOCKS ((NNODES + 255) / 256)   // 196
#define MTILE 64
#define LDW 136           // bf16 row stride in LDS
#define MAXD 64           // per-node LDS prefetch cap in gat_node

typedef __attribute__((ext_vector_type(8))) short short8;
typedef __attribute__((ext_vector_type(4))) float floatx4;

static __device__ inline unsigned short f2bf(float f) {
    unsigned u = __float_as_uint(f);
    return (unsigned short)((u + 0x7FFF + ((u >> 16) & 1)) >> 16);
}
static __device__ inline float bf2f(unsigned short u) {
    return __uint_as_float(((unsigned)u) << 16);
}

// ---------------------------------------------------------------------------
// Kernel 0: one-shot W fp32 -> bf16.
// ---------------------------------------------------------------------------
__global__ __launch_bounds__(256) void gat_wprep(
    const float* __restrict__ W, unsigned short* __restrict__ Wbf)
{
    int i = (blockIdx.x * 256 + threadIdx.x) * 4;   // 16 blocks
    float4 v = *(const float4*)(W + i);
    ushort4 u;
    u.x = f2bf(v.x); u.y = f2bf(v.y); u.z = f2bf(v.z); u.w = f2bf(v.w);
    *(ushort4*)(Wbf + i) = u;
}

// ---------------------------------------------------------------------------
// Kernel 1: h(bf16) = x @ W^T via bf16 MFMA (16x16x32), fused asrc/adst dots.
// Epilogue bounces C through LDS (reusing xl) for coalesced 16B h stores.
// ---------------------------------------------------------------------------
__global__ __launch_bounds__(256) void gat_gemm(
    const float* __restrict__ x, const unsigned short* __restrict__ Wbf,
    const float* __restrict__ att_src, const float* __restrict__ att_dst,
    unsigned short* __restrict__ h, float* __restrict__ asrc,
    float* __restrict__ adst)
{
    __shared__ unsigned short Wl[128 * LDW];
    __shared__ unsigned short xl[MTILE * LDW];
    const int t = threadIdx.x;
    const int rowBase = blockIdx.x * MTILE;

    for (int idx = t * 8; idx < 128 * 128; idx += 2048) {
        int r = idx >> 7, c = idx & 127;
        *(short8*)(Wl + r * LDW + c) = *(const short8*)(Wbf + idx);
    }
    for (int idx = t * 4; idx < MTILE * 128; idx += 1024) {
        int r = idx >> 7, c = idx & 127;
        int g = rowBase + r;
        float4 v = make_float4(0.f, 0.f, 0.f, 0.f);
        if (g < NNODES) v = *(const float4*)(x + (size_t)g * 128 + c);
        ushort4 u;
        u.x = f2bf(v.x); u.y = f2bf(v.y); u.z = f2bf(v.z); u.w = f2bf(v.w);
        *(ushort4*)(xl + r * LDW + c) = u;
    }
    __syncthreads();

    const int wave = t >> 6;
    const int lane = t & 63;
    const int c16  = lane & 15;
    const int quad = lane >> 4;

    floatx4 acc[8];
#pragma unroll
    for (int nt = 0; nt < 8; nt++) acc[nt] = (floatx4)(0.f);

#pragma unroll
    for (int kc = 0; kc < 4; kc++) {
        short8 av = *(const short8*)(xl + (wave * 16 + c16) * LDW + kc * 32 + quad * 8);
#pragma unroll
        for (int nt = 0; nt < 8; nt++) {
            short8 bv = *(const short8*)(Wl + (nt * 16 + c16) * LDW + kc * 32 + quad * 8);
            acc[nt] = __builtin_amdgcn_mfma_f32_16x16x32_bf16(av, bv, acc[nt], 0, 0, 0);
        }
    }

    // fused attention dots from acc registers
    float As[8], Ad[8];
#pragma unroll
    for (int nt = 0; nt < 8; nt++) {
        As[nt] = att_src[nt * 16 + c16];
        Ad[nt] = att_dst[nt * 16 + c16];
    }
#pragma unroll
    for (int r = 0; r < 4; r++) {
        const int gr = rowBase + wave * 16 + quad * 4 + r;
#pragma unroll
        for (int hh = 0; hh < 4; hh++) {
            float ps = acc[2 * hh][r] * As[2 * hh] + acc[2 * hh + 1][r] * As[2 * hh + 1];
            float pd = acc[2 * hh][r] * Ad[2 * hh] + acc[2 * hh + 1][r] * Ad[2 * hh + 1];
#pragma unroll
            for (int m = 8; m >= 1; m >>= 1) {
                ps += __shfl_xor(ps, m, 64);
                pd += __shfl_xor(pd, m, 64);
            }
            if (c16 == 0 && gr < NNODES) {
                asrc[gr * 4 + hh] = ps;
                adst[gr * 4 + hh] = pd;
            }
        }
    }

    // h write: bounce through LDS (xl free now), then coalesced short8 stores
    __syncthreads();
#pragma unroll
    for (int r = 0; r < 4; r++) {
        const int lr = wave * 16 + quad * 4 + r;
#pragma unroll
        for (int nt = 0; nt < 8; nt++)
            xl[lr * LDW + nt * 16 + c16] = f2bf(acc[nt][r]);
    }
    __syncthreads();
    for (int idx = t * 8; idx < MTILE * 128; idx += 2048) {
        int r = idx >> 7, c = idx & 127;
        int g = rowBase + r;
        if (g < NNODES)
            *(short8*)(h + (size_t)g * HD + c) = *(const short8*)(xl + r * LDW + c);
    }
}

// ---------------------------------------------------------------------------
// Kernel 2: degree histogram. Returned old value = edge's in-bucket rank.
// ---------------------------------------------------------------------------
__global__ __launch_bounds__(256) void gat_deg(
    const int* __restrict__ ei, int* __restrict__ deg, int* __restrict__ rank)
{
    int e = blockIdx.x * 256 + threadIdx.x;
    int d = ei[NEDGES + e];
    rank[e] = atomicAdd(deg + d, 1);
}

// ---------------------------------------------------------------------------
// Hierarchical exclusive scan of deg -> coff.
// ---------------------------------------------------------------------------
__global__ __launch_bounds__(256) void gat_scan1(
    const int* __restrict__ deg, int* __restrict__ coff, int* __restrict__ bsum)
{
    __shared__ int sh[256];
    const int t = threadIdx.x;
    const int i = blockIdx.x * 256 + t;
    int v = (i < NNODES) ? deg[i] : 0;
    sh[t] = v;
    __syncthreads();
    for (int off = 1; off < 256; off <<= 1) {
        int u = (t >= off) ? sh[t - off] : 0;
        __syncthreads();
        sh[t] += u;
        __syncthreads();
    }
    if (i < NNODES) coff[i] = sh[t] - v;
    if (t == 255) bsum[blockIdx.x] = sh[255];
}

__global__ __launch_bounds__(256) void gat_scan2(int* __restrict__ bsum)
{
    __shared__ int sh[256];
    const int t = threadIdx.x;
    int v = (t < SCAN_BLOCKS) ? bsum[t] : 0;
    sh[t] = v;
    __syncthreads();
    for (int off = 1; off < 256; off <<= 1) {
        int u = (t >= off) ? sh[t - off] : 0;
        __syncthreads();
        sh[t] += u;
        __syncthreads();
    }
    if (t < SCAN_BLOCKS) bsum[t] = sh[t] - v;
}

__global__ __launch_bounds__(256) void gat_scan3(
    int* __restrict__ coff, const int* __restrict__ bsum)
{
    const int i = blockIdx.x * 256 + threadIdx.x;
    if (i < NNODES) coff[i] += bsum[blockIdx.x];
    if (i == 0) coff[NNODES] = NEDGES;
}

// ---------------------------------------------------------------------------
// Kernel 4: CSR fill — NO atomics. pos = coff[d] + rank[e].
// ---------------------------------------------------------------------------
__global__ __launch_bounds__(256) void gat_fill(
    const int* __restrict__ ei, const int* __restrict__ rank,
    const float* __restrict__ asrc, const float* __restrict__ adst,
    const int* __restrict__ coff,
    int* __restrict__ csr_src, float* __restrict__ csr_w)
{
    int e = blockIdx.x * 256 + threadIdx.x;
    int s = ei[e], d = ei[NEDGES + e];
    float4 a = *(const float4*)(asrc + s * 4);
    float4 b = *(const float4*)(adst + d * 4);
    float al;
    al = a.x + b.x; al = (al > 0.f) ? al : NEG * al; float e0 = __expf(al);
    al = a.y + b.y; al = (al > 0.f) ? al : NEG * al; float e1 = __expf(al);
    al = a.z + b.z; al = (al > 0.f) ? al : NEG * al; float e2 = __expf(al);
    al = a.w + b.w; al = (al > 0.f) ? al : NEG * al; float e3 = __expf(al);
    int pos = coff[d] + rank[e];
    csr_src[pos] = s;
    *(float4*)(csr_w + (size_t)pos * 4) = make_float4(e0, e1, e2, e3);
}

// ---------------------------------------------------------------------------
// Kernel 5: per-node. Phase 1: sum bucket weights AND stash (src,w4) in LDS.
// Phase 2: normalize + gather h rows 4-way unrolled from LDS-held indices.
// 32 lanes/node, 8 nodes/block (grid divides exactly: 50000/8 = 6250).
// ---------------------------------------------------------------------------
__global__ __launch_bounds__(256) void gat_node(
    const int* __restrict__ coff, const int* __restrict__ csr_src,
    const float* __restrict__ csr_w, const unsigned short* __restrict__ h,
    const float* __restrict__ bias, float* __restrict__ out,
    float* __restrict__ ssum)
{
    __shared__ int   sh_src[8 * MAXD];
    __shared__ float sh_w[8 * MAXD * 4];
    int t = threadIdx.x;
    int node8 = t >> 5;                 // 0..7 within block
    int n = blockIdx.x * 8 + node8;
    int k = t & 31;
    int head = k >> 3;
    int beg = coff[n], end = coff[n + 1];

    // phase 1: weight sums + LDS stash of (src, w4)
    float4 sum = make_float4(0.f, 0.f, 0.f, 0.f);
    for (int j = beg + k; j < end; j += 32) {
        float4 wv = *(const float4*)(csr_w + (size_t)j * 4);
        sum.x += wv.x; sum.y += wv.y; sum.z += wv.z; sum.w += wv.w;
        int i = j - beg;
        if (i < MAXD) {
            sh_src[node8 * MAXD + i] = csr_src[j];
            *(float4*)(sh_w + (node8 * MAXD + i) * 4) = wv;
        }
    }
#pragma unroll
    for (int m = 16; m >= 1; m >>= 1) {
        sum.x += __shfl_xor(sum.x, m, 64);
        sum.y += __shfl_xor(sum.y, m, 64);
        sum.z += __shfl_xor(sum.z, m, 64);
        sum.w += __shfl_xor(sum.w, m, 64);
    }
    if (k == 0) *(float4*)(ssum + n * 4) = sum;
    float rs[4];
    rs[0] = 1.f / (sum.x + 1e-16f);
    rs[1] = 1.f / (sum.y + 1e-16f);
    rs[2] = 1.f / (sum.z + 1e-16f);
    rs[3] = 1.f / (sum.w + 1e-16f);
    const float rsel = rs[head];
    __syncthreads();

    // phase 2: gather h rows; src/w from LDS -> no global dependency chain
    const int cnt = end - beg;
    const int lim = (cnt < MAXD) ? cnt : MAXD;
    const int base = node8 * MAXD;
    float4 acc = *(const float4*)(bias + k * 4);
    float4 acc2 = make_float4(0.f, 0.f, 0.f, 0.f);
    int i = 0;
    for (; i + 4 <= lim; i += 4) {
        int s0 = sh_src[base + i];
        int s1 = sh_src[base + i + 1];
        int s2 = sh_src[base + i + 2];
        int s3 = sh_src[base + i + 3];
        float w0 = sh_w[(base + i) * 4 + head] * rsel;
        float w1 = sh_w[(base + i + 1) * 4 + head] * rsel;
        float w2 = sh_w[(base + i + 2) * 4 + head] * rsel;
        float w3 = sh_w[(base + i + 3) * 4 + head] * rsel;
        ushort4 u0 = *(const ushort4*)(h + (size_t)s0 * HD + k * 4);
        ushort4 u1 = *(const ushort4*)(h + (size_t)s1 * HD + k * 4);
        ushort4 u2 = *(const ushort4*)(h + (size_t)s2 * HD + k * 4);
        ushort4 u3 = *(const ushort4*)(h + (size_t)s3 * HD + k * 4);
        acc.x  = fmaf(bf2f(u0.x), w0, acc.x);
        acc.y  = fmaf(bf2f(u0.y), w0, acc.y);
        acc.z  = fmaf(bf2f(u0.z), w0, acc.z);
        acc.w  = fmaf(bf2f(u0.w), w0, acc.w);
        acc2.x = fmaf(bf2f(u1.x), w1, acc2.x);
        acc2.y = fmaf(bf2f(u1.y), w1, acc2.y);
        acc2.z = fmaf(bf2f(u1.z), w1, acc2.z);
        acc2.w = fmaf(bf2f(u1.w), w1, acc2.w);
        acc.x  = fmaf(bf2f(u2.x), w2, acc.x);
        acc.y  = fmaf(bf2f(u2.y), w2, acc.y);
        acc.z  = fmaf(bf2f(u2.z), w2, acc.z);
        acc.w  = fmaf(bf2f(u2.w), w2, acc.w);
        acc2.x = fmaf(bf2f(u3.x), w3, acc2.x);
        acc2.y = fmaf(bf2f(u3.y), w3, acc2.y);
        acc2.z = fmaf(bf2f(u3.z), w3, acc2.z);
        acc2.w = fmaf(bf2f(u3.w), w3, acc2.w);
    }
    for (; i < lim; i++) {
        int s0 = sh_src[base + i];
        float w0 = sh_w[(base + i) * 4 + head] * rsel;
        ushort4 u0 = *(const ushort4*)(h + (size_t)s0 * HD + k * 4);
        acc.x = fmaf(bf2f(u0.x), w0, acc.x);
        acc.y = fmaf(bf2f(u0.y), w0, acc.y);
        acc.z = fmaf(bf2f(u0.z), w0, acc.z);
        acc.w = fmaf(bf2f(u0.w), w0, acc.w);
    }
    for (int j = beg + MAXD; j < end; j++) {        // rare overflow fallback
        int s0 = csr_src[j];
        float w0 = csr_w[(size_t)j * 4 + head] * rsel;
        ushort4 u0 = *(const ushort4*)(h + (size_t)s0 * HD + k * 4);
        acc.x = fmaf(bf2f(u0.x), w0, acc.x);
        acc.y = fmaf(bf2f(u0.y), w0, acc.y);
        acc.z = fmaf(bf2f(u0.z), w0, acc.z);
        acc.w = fmaf(bf2f(u0.w), w0, acc.w);
    }
    acc.x += acc2.x; acc.y += acc2.y; acc.z += acc2.z; acc.w += acc2.w;
    *(float4*)(out + (size_t)n * HD + k * 4) = acc;
}

// ---------------------------------------------------------------------------
// Kernel 6: alpha_pooled from precomputed csr_w + ssum.
// ---------------------------------------------------------------------------
__global__ __launch_bounds__(256) void gat_apool(
    const int* __restrict__ ei, const int* __restrict__ rank,
    const int* __restrict__ coff, const float* __restrict__ csr_w,
    const float* __restrict__ ssum, float* __restrict__ apool)
{
    int e = blockIdx.x * 256 + threadIdx.x;
    int d = ei[NEDGES + e];
    int pos = coff[d] + rank[e];
    float4 wv = *(const float4*)(csr_w + (size_t)pos * 4);
    float4 sv = *(const float4*)(ssum + d * 4);
    apool[e] = 0.25f * (wv.x / (sv.x + 1e-16f) + wv.y / (sv.y + 1e-16f) +
                        wv.z / (sv.z + 1e-16f) + wv.w / (sv.w + 1e-16f));
}

// ---------------------------------------------------------------------------
extern "C" void kernel_launch(void* const* d_in, const int* in_sizes, int n_in,
                              void* d_out, int out_size, void* d_ws, size_t ws_size,
                              hipStream_t stream)
{
    const float* x       = (const float*)d_in[0];
    const int*   ei      = (const int*)d_in[1];
    const float* W       = (const float*)d_in[2];
    const float* att_src = (const float*)d_in[3];
    const float* att_dst = (const float*)d_in[4];
    const float* bias    = (const float*)d_in[5];

    float* out   = (float*)d_out;                    // (N,128)
    float* apool = out + (size_t)NNODES * HD;        // (E,)

    // workspace layout (16B-aligned chunks)
    unsigned short* h = (unsigned short*)d_ws;            // N*128 bf16
    float* asrc   = (float*)(h + (size_t)NNODES * HD);    // N*4
    float* adst   = asrc + NNODES * 4;               // N*4
    float* ssum   = adst + NNODES * 4;               // N*4
    float* csrw   = ssum + NNODES * 4;               // E*4
    int*   deg    = (int*)(csrw + (size_t)NEDGES * 4); // N
    int*   coff   = deg + NNODES;                    // N+1
    int*   rank   = coff + NNODES + 1;               // E
    int*   csrsrc = rank + NEDGES;                   // E
    int*   bsum   = csrsrc + NEDGES;                 // SCAN_BLOCKS
    unsigned short* wbf = (unsigned short*)(bsum + SCAN_BLOCKS + 2); // 16384

    hipMemsetAsync(deg, 0, (size_t)NNODES * sizeof(int), stream);

    gat_wprep<<<16, 256, 0, stream>>>(W, wbf);
    gat_gemm<<<(NNODES + MTILE - 1) / MTILE, 256, 0, stream>>>(
        x, wbf, att_src, att_dst, h, asrc, adst);
    gat_deg<<<NEDGES / 256, 256, 0, stream>>>(ei, deg, rank);
    gat_scan1<<<SCAN_BLOCKS, 256, 0, stream>>>(deg, coff, bsum);
    gat_scan2<<<1, 256, 0, stream>>>(bsum);
    gat_scan3<<<SCAN_BLOCKS, 256, 0, stream>>>(coff, bsum);
    gat_fill<<<NEDGES / 256, 256, 0, stream>>>(ei, rank, asrc, adst, coff, csrsrc, csrw);
    gat_node<<<NNODES / 8, 256, 0, stream>>>(coff, csrsrc, csrw, h, bias, out, ssum);
    gat_apool<<<NEDGES / 256, 256, 0, stream>>>(ei, rank, coff, csrw, ssum, apool);
}

// Round 9
// 205.707 us; speedup vs baseline: 8.1127x; 1.0907x over previous
//
#include <hip/hip_runtime.h>

#define NNODES 50000
#define NEDGES 800000
#define HD 128            // HEADS*OUT_DIM
#define NEG 0.2f
#define SCAN_BLOCKS ((NNODES + 255) / 256)   // 196
#define MTILE 64
#define LDW 136           // bf16 row stride in LDS
#define MAXD 64           // per-node LDS cache cap in gat_node

typedef __attribute__((ext_vector_type(8))) short short8;
typedef __attribute__((ext_vector_type(4))) float floatx4;

static __device__ inline unsigned short f2bf(float f) {
    unsigned u = __float_as_uint(f);
    return (unsigned short)((u + 0x7FFF + ((u >> 16) & 1)) >> 16);
}
static __device__ inline float bf2f(unsigned short u) {
    return __uint_as_float(((unsigned)u) << 16);
}
static __device__ inline float lrelu_exp(float a) {
    a = (a > 0.f) ? a : NEG * a;
    return __expf(a);
}

// ---------------------------------------------------------------------------
// Kernel 0: one-shot W fp32 -> bf16.
// ---------------------------------------------------------------------------
__global__ __launch_bounds__(256) void gat_wprep(
    const float* __restrict__ W, unsigned short* __restrict__ Wbf)
{
    int i = (blockIdx.x * 256 + threadIdx.x) * 4;   // 16 blocks
    float4 v = *(const float4*)(W + i);
    ushort4 u;
    u.x = f2bf(v.x); u.y = f2bf(v.y); u.z = f2bf(v.z); u.w = f2bf(v.w);
    *(ushort4*)(Wbf + i) = u;
}

// ---------------------------------------------------------------------------
// Kernel 1: h(bf16) = x @ W^T via bf16 MFMA (16x16x32), fused asrc/adst dots.
// Epilogue bounces C through LDS (reusing xl) for coalesced 16B h stores.
// ---------------------------------------------------------------------------
__global__ __launch_bounds__(256) void gat_gemm(
    const float* __restrict__ x, const unsigned short* __restrict__ Wbf,
    const float* __restrict__ att_src, const float* __restrict__ att_dst,
    unsigned short* __restrict__ h, float* __restrict__ asrc,
    float* __restrict__ adst)
{
    __shared__ unsigned short Wl[128 * LDW];
    __shared__ unsigned short xl[MTILE * LDW];
    const int t = threadIdx.x;
    const int rowBase = blockIdx.x * MTILE;

    for (int idx = t * 8; idx < 128 * 128; idx += 2048) {
        int r = idx >> 7, c = idx & 127;
        *(short8*)(Wl + r * LDW + c) = *(const short8*)(Wbf + idx);
    }
    for (int idx = t * 4; idx < MTILE * 128; idx += 1024) {
        int r = idx >> 7, c = idx & 127;
        int g = rowBase + r;
        float4 v = make_float4(0.f, 0.f, 0.f, 0.f);
        if (g < NNODES) v = *(const float4*)(x + (size_t)g * 128 + c);
        ushort4 u;
        u.x = f2bf(v.x); u.y = f2bf(v.y); u.z = f2bf(v.z); u.w = f2bf(v.w);
        *(ushort4*)(xl + r * LDW + c) = u;
    }
    __syncthreads();

    const int wave = t >> 6;
    const int lane = t & 63;
    const int c16  = lane & 15;
    const int quad = lane >> 4;

    floatx4 acc[8];
#pragma unroll
    for (int nt = 0; nt < 8; nt++) acc[nt] = (floatx4)(0.f);

#pragma unroll
    for (int kc = 0; kc < 4; kc++) {
        short8 av = *(const short8*)(xl + (wave * 16 + c16) * LDW + kc * 32 + quad * 8);
#pragma unroll
        for (int nt = 0; nt < 8; nt++) {
            short8 bv = *(const short8*)(Wl + (nt * 16 + c16) * LDW + kc * 32 + quad * 8);
            acc[nt] = __builtin_amdgcn_mfma_f32_16x16x32_bf16(av, bv, acc[nt], 0, 0, 0);
        }
    }

    float As[8], Ad[8];
#pragma unroll
    for (int nt = 0; nt < 8; nt++) {
        As[nt] = att_src[nt * 16 + c16];
        Ad[nt] = att_dst[nt * 16 + c16];
    }
#pragma unroll
    for (int r = 0; r < 4; r++) {
        const int gr = rowBase + wave * 16 + quad * 4 + r;
#pragma unroll
        for (int hh = 0; hh < 4; hh++) {
            float ps = acc[2 * hh][r] * As[2 * hh] + acc[2 * hh + 1][r] * As[2 * hh + 1];
            float pd = acc[2 * hh][r] * Ad[2 * hh] + acc[2 * hh + 1][r] * Ad[2 * hh + 1];
#pragma unroll
            for (int m = 8; m >= 1; m >>= 1) {
                ps += __shfl_xor(ps, m, 64);
                pd += __shfl_xor(pd, m, 64);
            }
            if (c16 == 0 && gr < NNODES) {
                asrc[gr * 4 + hh] = ps;
                adst[gr * 4 + hh] = pd;
            }
        }
    }

    __syncthreads();
#pragma unroll
    for (int r = 0; r < 4; r++) {
        const int lr = wave * 16 + quad * 4 + r;
#pragma unroll
        for (int nt = 0; nt < 8; nt++)
            xl[lr * LDW + nt * 16 + c16] = f2bf(acc[nt][r]);
    }
    __syncthreads();
    for (int idx = t * 8; idx < MTILE * 128; idx += 2048) {
        int r = idx >> 7, c = idx & 127;
        int g = rowBase + r;
        if (g < NNODES)
            *(short8*)(h + (size_t)g * HD + c) = *(const short8*)(xl + r * LDW + c);
    }
}

// ---------------------------------------------------------------------------
// Kernel 2: degree histogram. Returned old value = edge's in-bucket rank.
// ---------------------------------------------------------------------------
__global__ __launch_bounds__(256) void gat_deg(
    const int* __restrict__ ei, int* __restrict__ deg, int* __restrict__ rank)
{
    int e = blockIdx.x * 256 + threadIdx.x;
    int d = ei[NEDGES + e];
    rank[e] = atomicAdd(deg + d, 1);
}

// ---------------------------------------------------------------------------
// Hierarchical exclusive scan of deg -> coff.
// ---------------------------------------------------------------------------
__global__ __launch_bounds__(256) void gat_scan1(
    const int* __restrict__ deg, int* __restrict__ coff, int* __restrict__ bsum)
{
    __shared__ int sh[256];
    const int t = threadIdx.x;
    const int i = blockIdx.x * 256 + t;
    int v = (i < NNODES) ? deg[i] : 0;
    sh[t] = v;
    __syncthreads();
    for (int off = 1; off < 256; off <<= 1) {
        int u = (t >= off) ? sh[t - off] : 0;
        __syncthreads();
        sh[t] += u;
        __syncthreads();
    }
    if (i < NNODES) coff[i] = sh[t] - v;
    if (t == 255) bsum[blockIdx.x] = sh[255];
}

__global__ __launch_bounds__(256) void gat_scan2(int* __restrict__ bsum)
{
    __shared__ int sh[256];
    const int t = threadIdx.x;
    int v = (t < SCAN_BLOCKS) ? bsum[t] : 0;
    sh[t] = v;
    __syncthreads();
    for (int off = 1; off < 256; off <<= 1) {
        int u = (t >= off) ? sh[t - off] : 0;
        __syncthreads();
        sh[t] += u;
        __syncthreads();
    }
    if (t < SCAN_BLOCKS) bsum[t] = sh[t] - v;
}

__global__ __launch_bounds__(256) void gat_scan3(
    int* __restrict__ coff, const int* __restrict__ bsum)
{
    const int i = blockIdx.x * 256 + threadIdx.x;
    if (i < NNODES) coff[i] += bsum[blockIdx.x];
    if (i == 0) coff[NNODES] = NEDGES;
}

// ---------------------------------------------------------------------------
// Kernel 4: CSR fill — only the 4B src index is scattered now (weights are
// recomputed from L2-resident asrc/adst where needed).
// ---------------------------------------------------------------------------
__global__ __launch_bounds__(256) void gat_fill(
    const int* __restrict__ ei, const int* __restrict__ rank,
    const int* __restrict__ coff, int* __restrict__ csr_src)
{
    int e = blockIdx.x * 256 + threadIdx.x;
    int s = ei[e], d = ei[NEDGES + e];
    csr_src[coff[d] + rank[e]] = s;
}

// ---------------------------------------------------------------------------
// Kernel 5: per-node. Phase 1: gather asrc[src] (L2-resident, 800KB), compute
// exp weights on the fly, sum per head, stash (src,w4) in LDS. Phase 2:
// normalize + gather h rows 4-way unrolled. 32 lanes/node, 8 nodes/block.
// ---------------------------------------------------------------------------
__global__ __launch_bounds__(256) void gat_node(
    const int* __restrict__ coff, const int* __restrict__ csr_src,
    const float* __restrict__ asrc, const float* __restrict__ adst,
    const unsigned short* __restrict__ h, const float* __restrict__ bias,
    float* __restrict__ out, float* __restrict__ ssum)
{
    __shared__ int   sh_src[8 * MAXD];
    __shared__ float sh_w[8 * MAXD * 4];
    int t = threadIdx.x;
    int node8 = t >> 5;
    int n = blockIdx.x * 8 + node8;
    int k = t & 31;
    int head = k >> 3;
    int beg = coff[n], end = coff[n + 1];
    const float4 bn = *(const float4*)(adst + n * 4);   // per-node broadcast

    // phase 1: weight compute + sums + LDS stash
    float4 sum = make_float4(0.f, 0.f, 0.f, 0.f);
    for (int j = beg + k; j < end; j += 32) {
        int s = csr_src[j];
        float4 a = *(const float4*)(asrc + s * 4);
        float4 wv;
        wv.x = lrelu_exp(a.x + bn.x);
        wv.y = lrelu_exp(a.y + bn.y);
        wv.z = lrelu_exp(a.z + bn.z);
        wv.w = lrelu_exp(a.w + bn.w);
        sum.x += wv.x; sum.y += wv.y; sum.z += wv.z; sum.w += wv.w;
        int i = j - beg;
        if (i < MAXD) {
            sh_src[node8 * MAXD + i] = s;
            *(float4*)(sh_w + (node8 * MAXD + i) * 4) = wv;
        }
    }
#pragma unroll
    for (int m = 16; m >= 1; m >>= 1) {
        sum.x += __shfl_xor(sum.x, m, 64);
        sum.y += __shfl_xor(sum.y, m, 64);
        sum.z += __shfl_xor(sum.z, m, 64);
        sum.w += __shfl_xor(sum.w, m, 64);
    }
    if (k == 0) *(float4*)(ssum + n * 4) = sum;
    float rs[4];
    rs[0] = 1.f / (sum.x + 1e-16f);
    rs[1] = 1.f / (sum.y + 1e-16f);
    rs[2] = 1.f / (sum.z + 1e-16f);
    rs[3] = 1.f / (sum.w + 1e-16f);
    const float rsel = rs[head];
    __syncthreads();

    // phase 2: gather h rows; src/w from LDS -> no global dependency chain
    const int cnt = end - beg;
    const int lim = (cnt < MAXD) ? cnt : MAXD;
    const int base = node8 * MAXD;
    float4 acc = *(const float4*)(bias + k * 4);
    float4 acc2 = make_float4(0.f, 0.f, 0.f, 0.f);
    int i = 0;
    for (; i + 4 <= lim; i += 4) {
        int s0 = sh_src[base + i];
        int s1 = sh_src[base + i + 1];
        int s2 = sh_src[base + i + 2];
        int s3 = sh_src[base + i + 3];
        float w0 = sh_w[(base + i) * 4 + head] * rsel;
        float w1 = sh_w[(base + i + 1) * 4 + head] * rsel;
        float w2 = sh_w[(base + i + 2) * 4 + head] * rsel;
        float w3 = sh_w[(base + i + 3) * 4 + head] * rsel;
        ushort4 u0 = *(const ushort4*)(h + (size_t)s0 * HD + k * 4);
        ushort4 u1 = *(const ushort4*)(h + (size_t)s1 * HD + k * 4);
        ushort4 u2 = *(const ushort4*)(h + (size_t)s2 * HD + k * 4);
        ushort4 u3 = *(const ushort4*)(h + (size_t)s3 * HD + k * 4);
        acc.x  = fmaf(bf2f(u0.x), w0, acc.x);
        acc.y  = fmaf(bf2f(u0.y), w0, acc.y);
        acc.z  = fmaf(bf2f(u0.z), w0, acc.z);
        acc.w  = fmaf(bf2f(u0.w), w0, acc.w);
        acc2.x = fmaf(bf2f(u1.x), w1, acc2.x);
        acc2.y = fmaf(bf2f(u1.y), w1, acc2.y);
        acc2.z = fmaf(bf2f(u1.z), w1, acc2.z);
        acc2.w = fmaf(bf2f(u1.w), w1, acc2.w);
        acc.x  = fmaf(bf2f(u2.x), w2, acc.x);
        acc.y  = fmaf(bf2f(u2.y), w2, acc.y);
        acc.z  = fmaf(bf2f(u2.z), w2, acc.z);
        acc.w  = fmaf(bf2f(u2.w), w2, acc.w);
        acc2.x = fmaf(bf2f(u3.x), w3, acc2.x);
        acc2.y = fmaf(bf2f(u3.y), w3, acc2.y);
        acc2.z = fmaf(bf2f(u3.z), w3, acc2.z);
        acc2.w = fmaf(bf2f(u3.w), w3, acc2.w);
    }
    for (; i < lim; i++) {
        int s0 = sh_src[base + i];
        float w0 = sh_w[(base + i) * 4 + head] * rsel;
        ushort4 u0 = *(const ushort4*)(h + (size_t)s0 * HD + k * 4);
        acc.x = fmaf(bf2f(u0.x), w0, acc.x);
        acc.y = fmaf(bf2f(u0.y), w0, acc.y);
        acc.z = fmaf(bf2f(u0.z), w0, acc.z);
        acc.w = fmaf(bf2f(u0.w), w0, acc.w);
    }
    for (int j = beg + MAXD; j < end; j++) {        // rare overflow fallback
        int s0 = csr_src[j];
        float4 a = *(const float4*)(asrc + s0 * 4);
        float w4[4];
        w4[0] = lrelu_exp(a.x + bn.x);
        w4[1] = lrelu_exp(a.y + bn.y);
        w4[2] = lrelu_exp(a.z + bn.z);
        w4[3] = lrelu_exp(a.w + bn.w);
        float w0 = w4[head] * rsel;
        ushort4 u0 = *(const ushort4*)(h + (size_t)s0 * HD + k * 4);
        acc.x = fmaf(bf2f(u0.x), w0, acc.x);
        acc.y = fmaf(bf2f(u0.y), w0, acc.y);
        acc.z = fmaf(bf2f(u0.z), w0, acc.z);
        acc.w = fmaf(bf2f(u0.w), w0, acc.w);
    }
    acc.x += acc2.x; acc.y += acc2.y; acc.z += acc2.z; acc.w += acc2.w;
    *(float4*)(out + (size_t)n * HD + k * 4) = acc;
}

// ---------------------------------------------------------------------------
// Kernel 6: alpha_pooled, edge-order; recompute exp from L2-resident
// asrc/adst/ssum (no CSR indirection).
// ---------------------------------------------------------------------------
__global__ __launch_bounds__(256) void gat_apool(
    const int* __restrict__ ei, const float* __restrict__ asrc,
    const float* __restrict__ adst, const float* __restrict__ ssum,
    float* __restrict__ apool)
{
    int e = blockIdx.x * 256 + threadIdx.x;
    int s = ei[e], d = ei[NEDGES + e];
    float4 a  = *(const float4*)(asrc + s * 4);
    float4 b  = *(const float4*)(adst + d * 4);
    float4 sv = *(const float4*)(ssum + d * 4);
    float w0 = lrelu_exp(a.x + b.x) / (sv.x + 1e-16f);
    float w1 = lrelu_exp(a.y + b.y) / (sv.y + 1e-16f);
    float w2 = lrelu_exp(a.z + b.z) / (sv.z + 1e-16f);
    float w3 = lrelu_exp(a.w + b.w) / (sv.w + 1e-16f);
    apool[e] = 0.25f * (w0 + w1 + w2 + w3);
}

// ---------------------------------------------------------------------------
extern "C" void kernel_launch(void* const* d_in, const int* in_sizes, int n_in,
                              void* d_out, int out_size, void* d_ws, size_t ws_size,
                              hipStream_t stream)
{
    const float* x       = (const float*)d_in[0];
    const int*   ei      = (const int*)d_in[1];
    const float* W       = (const float*)d_in[2];
    const float* att_src = (const float*)d_in[3];
    const float* att_dst = (const float*)d_in[4];
    const float* bias    = (const float*)d_in[5];

    float* out   = (float*)d_out;                    // (N,128)
    float* apool = out + (size_t)NNODES * HD;        // (E,)

    // workspace layout (16B-aligned chunks); csr_w eliminated
    unsigned short* h = (unsigned short*)d_ws;            // N*128 bf16
    float* asrc   = (float*)(h + (size_t)NNODES * HD);    // N*4
    float* adst   = asrc + NNODES * 4;               // N*4
    float* ssum   = adst + NNODES * 4;               // N*4
    int*   deg    = (int*)(ssum + NNODES * 4);       // N
    int*   coff   = deg + NNODES;                    // N+1
    int*   rank   = coff + NNODES + 1;               // E
    int*   csrsrc = rank + NEDGES;                   // E
    int*   bsum   = csrsrc + NEDGES;                 // SCAN_BLOCKS
    unsigned short* wbf = (unsigned short*)(bsum + SCAN_BLOCKS + 2); // 16384

    hipMemsetAsync(deg, 0, (size_t)NNODES * sizeof(int), stream);

    gat_wprep<<<16, 256, 0, stream>>>(W, wbf);
    gat_gemm<<<(NNODES + MTILE - 1) / MTILE, 256, 0, stream>>>(
        x, wbf, att_src, att_dst, h, asrc, adst);
    gat_deg<<<NEDGES / 256, 256, 0, stream>>>(ei, deg, rank);
    gat_scan1<<<SCAN_BLOCKS, 256, 0, stream>>>(deg, coff, bsum);
    gat_scan2<<<1, 256, 0, stream>>>(bsum);
    gat_scan3<<<SCAN_BLOCKS, 256, 0, stream>>>(coff, bsum);
    gat_fill<<<NEDGES / 256, 256, 0, stream>>>(ei, rank, coff, csrsrc);
    gat_node<<<NNODES / 8, 256, 0, stream>>>(coff, csrsrc, asrc, adst, h, bias, out, ssum);
    gat_apool<<<NEDGES / 256, 256, 0, stream>>>(ei, asrc, adst, ssum, apool);
}